// Round 12
// baseline (254.061 us; speedup 1.0000x reference)
//
#include <hip/hip_runtime.h>
#include <cstdint>
#include <cstddef>

// ---------- types ----------
typedef __attribute__((ext_vector_type(8))) short short8;   // 8 bf16 MFMA A/B frag
typedef __attribute__((ext_vector_type(4))) float f32x4;    // 16x16 C/D frag
typedef __attribute__((ext_vector_type(16))) float f32x16;  // 32x32 C/D frag

#define MFMA16(a, b, c) __builtin_amdgcn_mfma_f32_16x16x32_bf16((a), (b), (c), 0, 0, 0)
#define MFMA32(a, b, c) __builtin_amdgcn_mfma_f32_32x32x16_bf16((a), (b), (c), 0, 0, 0)

union F2U { float f; unsigned int u; };
union U4S8 { uint4 u4; unsigned short s[8]; short8 v; };

__device__ __forceinline__ unsigned short f2bf(float f) {
  F2U x; x.f = f;
  unsigned int r = x.u + 0x7fffu + ((x.u >> 16) & 1u);  // RNE
  return (unsigned short)(r >> 16);
}
__device__ __forceinline__ float bf2f(unsigned short s) {
  F2U x; x.u = ((unsigned int)s) << 16;
  return x.f;
}
__device__ __forceinline__ float fexp2(float x) {        // v_exp_f32: D = 2^S0
  float r; asm("v_exp_f32 %0, %1" : "=v"(r) : "v"(x)); return r;
}
__device__ __forceinline__ unsigned int cvtpk(float lo, float hiv) {  // T12
  unsigned int r; asm("v_cvt_pk_bf16_f32 %0, %1, %2" : "=v"(r) : "v"(lo), "v"(hiv)); return r;
}

// ---------- problem constants ----------
#define HIDDEN 2048
#define NHEADS 32
#define NKV 8
#define HDIM 64
#define SEQ 2048
#define BATCH 2
#define NTOK (BATCH * SEQ)   // 4096
#define QKVN 3072            // fused QKV output width (2048 Q | 512 K | 512 V)
#define QSCALE 0.18033688011117309f   // 0.125 * log2(e)

// =====================================================================
// RoPE table: cos/sin [SEQ][32] fp32
// =====================================================================
__global__ __launch_bounds__(256) void rope_table_kernel(float* __restrict__ ct, float* __restrict__ st) {
  int idx = blockIdx.x * 256 + threadIdx.x;     // 0 .. 65535
  int s = idx >> 5;
  int i = idx & 31;
  float invf = expf(-(float)i * (9.210340371976184f / 32.0f));  // 10000^(-i/32)
  float f = (float)s * invf;
  ct[idx] = cosf(f);
  st[idx] = sinf(f);
}

// =====================================================================
// X fp32 -> bf16 (elementwise, vectorized)
// =====================================================================
__global__ __launch_bounds__(256) void convert_x_kernel(const float* __restrict__ X,
                                                        unsigned short* __restrict__ Xb) {
  size_t i = ((size_t)blockIdx.x * 256 + threadIdx.x) * 8;
  float4 a0 = *(const float4*)(X + i);
  float4 a1 = *(const float4*)(X + i + 4);
  U4S8 p;
  p.s[0] = f2bf(a0.x); p.s[1] = f2bf(a0.y); p.s[2] = f2bf(a0.z); p.s[3] = f2bf(a0.w);
  p.s[4] = f2bf(a1.x); p.s[5] = f2bf(a1.y); p.s[6] = f2bf(a1.z); p.s[7] = f2bf(a1.w);
  *(short8*)(Xb + i) = p.v;
}

// =====================================================================
// Weight transpose+convert: W [K=2048][N] fp32 -> Wt[row_off + n][k] bf16
// =====================================================================
__global__ __launch_bounds__(256) void transpose_w_kernel(const float* __restrict__ W,
                                                          unsigned short* __restrict__ Wt,
                                                          int N, int row_off) {
  __shared__ unsigned short lt[64][72];  // [n][k], padded
  const int t = threadIdx.x;
  const int k0 = blockIdx.y * 64, n0 = blockIdx.x * 64;
  #pragma unroll
  for (int p = 0; p < 4; ++p) {
    int kr = p * 16 + (t >> 4);
    int nc = (t & 15) * 4;
    float4 v = *(const float4*)&W[(size_t)(k0 + kr) * N + n0 + nc];
    lt[nc + 0][kr] = f2bf(v.x);
    lt[nc + 1][kr] = f2bf(v.y);
    lt[nc + 2][kr] = f2bf(v.z);
    lt[nc + 3][kr] = f2bf(v.w);
  }
  __syncthreads();
  #pragma unroll
  for (int p = 0; p < 2; ++p) {
    int nr = p * 32 + (t >> 3);
    int kc = (t & 7) * 8;
    *(short8*)&Wt[(size_t)(row_off + n0 + nr) * HIDDEN + k0 + kc] = *(const short8*)&lt[nr][kc];
  }
}

// =====================================================================
// GEMM (m97-class): C[M,N] = A[M,K] @ Bt[N,K]^T, all bf16 operands.
// 128x128 tile, BK=64, 4 waves; global_load_lds w16 + XOR chunk swizzle.
// T1 XCD-aware block swizzle (bijective: nwg % 8 == 0 for both grids).
// MODE 0: fp32 out. MODE 1: bf16 out with FUSED ROPE for QKV.
// =====================================================================
template<int MODE>
__global__ __launch_bounds__(256) void gemm128_kernel(const unsigned short* __restrict__ Ab,
                                                      const unsigned short* __restrict__ Bt,
                                                      void* __restrict__ Cp,
                                                      int M, int N, int K,
                                                      const float* __restrict__ ct,
                                                      const float* __restrict__ st) {
  __shared__ __align__(16) unsigned short lds_a[128][64];
  __shared__ __align__(16) unsigned short lds_b[128][64];

  const int t = threadIdx.x, lane = t & 63, w = t >> 6;
  const int lr = lane & 15, lh = lane >> 4;

  // T1: XCD-aware swizzle — contiguous tile chunk per XCD
  const int orig = blockIdx.y * gridDim.x + blockIdx.x;
  const int nwg  = (int)(gridDim.x * gridDim.y);
  const int cpx  = nwg >> 3;                      // nwg % 8 == 0
  const int swz  = (orig & 7) * cpx + (orig >> 3);
  const int m0 = (swz / (int)gridDim.x) * 128;
  const int n0 = (swz % (int)gridDim.x) * 128;

  const int wr = (w >> 1) * 64, wc = (w & 1) * 64;

  f32x4 acc[4][4] = {};

  for (int k0 = 0; k0 < K; k0 += 64) {
    __syncthreads();
    #pragma unroll
    for (int c = 0; c < 4; ++c) {
      int row = w * 32 + c * 8 + (lane >> 3);
      int cks = (lane & 7) ^ (row & 7);
      __builtin_amdgcn_global_load_lds(
          (const __attribute__((address_space(1))) unsigned int*)(Ab + (size_t)(m0 + row) * K + k0 + cks * 8),
          (__attribute__((address_space(3))) unsigned int*)&lds_a[w * 32 + c * 8][0], 16, 0, 0);
      __builtin_amdgcn_global_load_lds(
          (const __attribute__((address_space(1))) unsigned int*)(Bt + (size_t)(n0 + row) * K + k0 + cks * 8),
          (__attribute__((address_space(3))) unsigned int*)&lds_b[w * 32 + c * 8][0], 16, 0, 0);
    }
    __syncthreads();

    #pragma unroll
    for (int kk = 0; kk < 2; ++kk) {
      short8 af[4], bf[4];
      #pragma unroll
      for (int i = 0; i < 4; ++i) {
        int row = wr + i * 16 + lr;
        af[i] = *(const short8*)((const char*)&lds_a[0][0] + row * 128 + (((kk * 4 + lh) ^ (row & 7)) * 16));
      }
      #pragma unroll
      for (int j = 0; j < 4; ++j) {
        int row = wc + j * 16 + lr;
        bf[j] = *(const short8*)((const char*)&lds_b[0][0] + row * 128 + (((kk * 4 + lh) ^ (row & 7)) * 16));
      }
      #pragma unroll
      for (int i = 0; i < 4; ++i)
        #pragma unroll
        for (int j = 0; j < 4; ++j)
          acc[i][j] = MFMA16(af[i], bf[j], acc[i][j]);
    }
  }

  if constexpr (MODE == 0) {
    #pragma unroll
    for (int i = 0; i < 4; ++i)
      #pragma unroll
      for (int j = 0; j < 4; ++j)
        #pragma unroll
        for (int r = 0; r < 4; ++r) {
          int row = m0 + wr + i * 16 + lh * 4 + r;
          int col = n0 + wc + j * 16 + lr;
          ((float*)Cp)[(size_t)row * N + col] = acc[i][j][r];
        }
  } else {
    const bool isV = (n0 >= 2560);
    const bool isQ = (n0 < 2048);
    #pragma unroll
    for (int i = 0; i < 4; ++i)
      #pragma unroll
      for (int r = 0; r < 4; ++r) {
        int row = m0 + wr + i * 16 + lh * 4 + r;
        int s_tok = row & (SEQ - 1);
        float c0 = 0.f, s0 = 0.f, c1 = 0.f, s1 = 0.f;
        if (!isV) {
          c0 = ct[s_tok * 32 + lr];      s0 = st[s_tok * 32 + lr];
          c1 = ct[s_tok * 32 + 16 + lr]; s1 = st[s_tok * 32 + 16 + lr];
        }
        #pragma unroll
        for (int j = 0; j < 4; ++j) {
          int col = n0 + wc + j * 16 + lr;
          float v = acc[i][j][r];
          float o;
          if (isV) {
            o = v;
          } else {
            float p = acc[i][j ^ 2][r];          // partner col^32 (const idx)
            float cc = (j & 1) ? c1 : c0;
            float ss = (j & 1) ? s1 : s0;
            o = v * cc + ((j & 2) ? p : -p) * ss;  // rotate_half sign
            if (isQ) o *= QSCALE;
          }
          ((unsigned short*)Cp)[(size_t)row * N + col] = f2bf(o);
        }
      }
  }
}

// =====================================================================
// V pack/transpose: QKVb cols 2560.. -> Vt [B][KV][64][S] bf16
// =====================================================================
__global__ __launch_bounds__(256) void v_pack_kernel(const unsigned short* __restrict__ QKV,
                                                     unsigned short* __restrict__ Vt) {
  int idx = blockIdx.x * 256 + threadIdx.x;
  int m = idx >> 9;
  int c = idx & 511;
  int b = m >> 11, s = m & 2047;
  int kv = c >> 6, d = c & 63;
  Vt[(((size_t)(b * NKV + kv)) * HDIM + d) * SEQ + s] = QKV[(size_t)m * QKVN + 2560 + c];
}

// =====================================================================
// Flash attention: 4 waves x 32 q-rows (Q-tile 128), KVBLK=64
// cooperative dbuf LDS staging for K and V, swapped QK^T 32x32 MFMA.
// FULL tiles use a FUSED 64-key softmax (both halves' QK MFMAs
// interleaved, ONE max/rescale/sum pass) — halves the serial reduction
// chain per tile. Last (diagonal) tile uses the per-half masked path.
// exp2-domain softmax, T12 cvt_pk, T13 defer-max (THR=11). All P
// selects use compile-time-constant indices (rule #20).
// =====================================================================
#define KVBLK 64

__global__ __launch_bounds__(256, 4) void flash_kernel(const unsigned short* __restrict__ QKV,
                                                       const unsigned short* __restrict__ Vt,
                                                       unsigned short* __restrict__ Ob) {
  const int qb = (int)gridDim.x - 1 - (int)blockIdx.x;  // heavy blocks first
  const int h = blockIdx.y;
  const int b = blockIdx.z;
  const int kv = h >> 2;
  const int t = threadIdx.x;
  const int lane = t & 63;
  const int w = t >> 6;          // 0..3
  const int q = lane & 31;
  const int hi = lane >> 5;

  // [0,16384): K dbuf [2][64][64] bf16 ; [16384,32768): V dbuf [2][64][64]
  // epilogue: region reused as per-wave transpose buffers [4][32*72]
  __shared__ __align__(16) char smem[32768];
  unsigned short* Klds = (unsigned short*)smem;
  unsigned short* Vlds = (unsigned short*)(smem + 16384);

  const unsigned short* Kg = QKV + (size_t)b * SEQ * QKVN + 2048 + kv * 64;
  const unsigned short* Vg = Vt + ((size_t)(b * NKV + kv)) * HDIM * SEQ;

  const int wq0 = qb * 128 + w * 32;

  // Q B-frags (pre-scaled by 0.125*log2e in GEMM epilogue)
  const unsigned short* Qh = QKV + (size_t)b * SEQ * QKVN + h * 64;
  short8 qf[4];
  #pragma unroll
  for (int f = 0; f < 4; ++f)
    qf[f] = *(const short8*)&Qh[(size_t)(wq0 + q) * QKVN + f * 16 + hi * 8];

  // staging: wave w covers rows [w*16, w*16+16), two 8-row groups.
  const int srow = w * 16 + (lane >> 3);
  const int scks = (lane & 7) ^ (srow & 7);      // (srow+8)&7 == srow&7
  const unsigned short* Ksrc = Kg + (size_t)srow * QKVN + scks * 8;   // + kt0*QKVN
  const unsigned short* Vsrc = Vg + (size_t)srow * SEQ + scks * 8;    // + kt0

  #define STAGE_KV(buf, kt0)                                                              \
    do {                                                                                  \
      __builtin_amdgcn_global_load_lds(                                                   \
          (const __attribute__((address_space(1))) unsigned int*)(Ksrc + (size_t)(kt0) * QKVN), \
          (__attribute__((address_space(3))) unsigned int*)(Klds + (buf) * 4096 + w * 1024), 16, 0, 0); \
      __builtin_amdgcn_global_load_lds(                                                   \
          (const __attribute__((address_space(1))) unsigned int*)(Ksrc + (size_t)(kt0) * QKVN + 8 * QKVN), \
          (__attribute__((address_space(3))) unsigned int*)(Klds + (buf) * 4096 + w * 1024 + 512), 16, 0, 0); \
      __builtin_amdgcn_global_load_lds(                                                   \
          (const __attribute__((address_space(1))) unsigned int*)(Vsrc + (kt0)),          \
          (__attribute__((address_space(3))) unsigned int*)(Vlds + (buf) * 4096 + w * 1024), 16, 0, 0); \
      __builtin_amdgcn_global_load_lds(                                                   \
          (const __attribute__((address_space(1))) unsigned int*)(Vsrc + (kt0) + 8 * SEQ), \
          (__attribute__((address_space(3))) unsigned int*)(Vlds + (buf) * 4096 + w * 1024 + 512), 16, 0, 0); \
    } while (0)

  f32x16 o0 = {}, o1 = {};
  float m_run = -1e30f, l_run = 0.f;

  const int nt_blk = qb * 2 + 2;            // tiles staged by the block
  const int nt_w   = qb * 2 + (w >> 1) + 1; // tiles this wave computes

  STAGE_KV(0, 0);
  __syncthreads();
  int cur = 0;

  for (int tt = 0; tt < nt_blk; ++tt) {
    if (tt + 1 < nt_blk) STAGE_KV(cur ^ 1, (tt + 1) * KVBLK);

    if (tt < nt_w) {
      const int kt0 = tt * KVBLK;
      const unsigned short* Kt = Klds + cur * 4096;
      const unsigned short* Vl = Vlds + cur * 4096;

      if (tt + 1 < nt_w) {
        // ======== FAST PATH: full 64-key tile, fused softmax ========
        f32x16 sA = {}, sB = {};
        __builtin_amdgcn_s_setprio(1);
        #pragma unroll
        for (int f = 0; f < 4; ++f) {
          int co = ((f * 2 + hi) ^ (q & 7)) * 8;
          short8 kfA = *(const short8*)(Kt + q * 64 + co);
          short8 kfB = *(const short8*)(Kt + (32 + q) * 64 + co);
          sA = MFMA32(kfA, qf[f], sA);
          sB = MFMA32(kfB, qf[f], sB);
        }
        __builtin_amdgcn_s_setprio(0);

        float mt = -1e30f;
        #pragma unroll
        for (int r = 0; r < 16; ++r) mt = fmaxf(mt, fmaxf(sA[r], sB[r]));
        mt = fmaxf(mt, __shfl_xor(mt, 32, 64));

        const bool resc = __any(mt > m_run + 11.0f);
        if (resc) {
          float mn = fmaxf(m_run, mt);
          float alpha = fexp2(m_run - mn);
          m_run = mn;
          l_run *= alpha;
          #pragma unroll
          for (int r = 0; r < 16; ++r) { o0[r] *= alpha; o1[r] *= alpha; }
        }
        float ls = 0.f;
        #pragma unroll
        for (int r = 0; r < 16; ++r) {
          sA[r] = fexp2(sA[r] - m_run);
          sB[r] = fexp2(sB[r] - m_run);
          ls += sA[r] + sB[r];
        }
        ls += __shfl_xor(ls, 32, 64);
        l_run += ls;

        unsigned int ownA[8], rcvA[8], ownB[8], rcvB[8];
        #pragma unroll
        for (int g = 0; g < 8; ++g) {
          ownA[g] = cvtpk(sA[2 * g], sA[2 * g + 1]);
          ownB[g] = cvtpk(sB[2 * g], sB[2 * g + 1]);
        }
        #pragma unroll
        for (int g = 0; g < 8; ++g) {
          rcvA[g] = (unsigned int)__shfl_xor((int)ownA[g], 32, 64);
          rcvB[g] = (unsigned int)__shfl_xor((int)ownB[g], 32, 64);
        }

        __builtin_amdgcn_s_setprio(1);
        {
          U4S8 pfv;
          pfv.u4.x = hi ? rcvA[2] : ownA[0];
          pfv.u4.y = hi ? rcvA[3] : ownA[1];
          pfv.u4.z = hi ? ownA[2] : rcvA[0];
          pfv.u4.w = hi ? ownA[3] : rcvA[1];
          int co = (hi ^ (q & 7)) * 8;
          short8 vf0 = *(const short8*)(Vl + q * 64 + co);
          short8 vf1 = *(const short8*)(Vl + (32 + q) * 64 + co);
          o0 = MFMA32(vf0, pfv.v, o0);
          o1 = MFMA32(vf1, pfv.v, o1);
        }
        {
          U4S8 pfv;
          pfv.u4.x = hi ? rcvA[6] : ownA[4];
          pfv.u4.y = hi ? rcvA[7] : ownA[5];
          pfv.u4.z = hi ? ownA[6] : rcvA[4];
          pfv.u4.w = hi ? ownA[7] : rcvA[5];
          int co = ((2 + hi) ^ (q & 7)) * 8;
          short8 vf0 = *(const short8*)(Vl + q * 64 + co);
          short8 vf1 = *(const short8*)(Vl + (32 + q) * 64 + co);
          o0 = MFMA32(vf0, pfv.v, o0);
          o1 = MFMA32(vf1, pfv.v, o1);
        }
        {
          U4S8 pfv;
          pfv.u4.x = hi ? rcvB[2] : ownB[0];
          pfv.u4.y = hi ? rcvB[3] : ownB[1];
          pfv.u4.z = hi ? ownB[2] : rcvB[0];
          pfv.u4.w = hi ? ownB[3] : rcvB[1];
          int co = ((4 + hi) ^ (q & 7)) * 8;
          short8 vf0 = *(const short8*)(Vl + q * 64 + co);
          short8 vf1 = *(const short8*)(Vl + (32 + q) * 64 + co);
          o0 = MFMA32(vf0, pfv.v, o0);
          o1 = MFMA32(vf1, pfv.v, o1);
        }
        {
          U4S8 pfv;
          pfv.u4.x = hi ? rcvB[6] : ownB[4];
          pfv.u4.y = hi ? rcvB[7] : ownB[5];
          pfv.u4.z = hi ? ownB[6] : rcvB[4];
          pfv.u4.w = hi ? ownB[7] : rcvB[5];
          int co = ((6 + hi) ^ (q & 7)) * 8;
          short8 vf0 = *(const short8*)(Vl + q * 64 + co);
          short8 vf1 = *(const short8*)(Vl + (32 + q) * 64 + co);
          o0 = MFMA32(vf0, pfv.v, o0);
          o1 = MFMA32(vf1, pfv.v, o1);
        }
        __builtin_amdgcn_s_setprio(0);
      } else {
        // ======== LAST TILE: per-half with causal mask ========
        #pragma unroll
        for (int hk = 0; hk < 2; ++hk) {
          const int kbase = kt0 + hk * 32;
          if (kbase <= wq0 + 31) {          // wave-uniform: not fully masked
            f32x16 s = {};
            __builtin_amdgcn_s_setprio(1);
            #pragma unroll
            for (int f = 0; f < 4; ++f) {
              short8 kf = *(const short8*)(Kt + (hk * 32 + q) * 64 + (((f * 2 + hi) ^ (q & 7)) * 8));
              s = MFMA32(kf, qf[f], s);
            }
            __builtin_amdgcn_s_setprio(0);

            if (kbase + 31 > wq0) {
              #pragma unroll
              for (int r = 0; r < 16; ++r) {
                int kl = (r & 3) + 8 * (r >> 2) + 4 * hi;
                if (kbase + kl > wq0 + q) s[r] = -1e30f;
              }
            }

            float mt = -1e30f;
            #pragma unroll
            for (int r = 0; r < 16; ++r) mt = fmaxf(mt, s[r]);
            mt = fmaxf(mt, __shfl_xor(mt, 32, 64));

            const bool resc = __any(mt > m_run + 11.0f);
            if (resc) {
              float mn = fmaxf(m_run, mt);
              float alpha = fexp2(m_run - mn);
              m_run = mn;
              l_run *= alpha;
              #pragma unroll
              for (int r = 0; r < 16; ++r) { o0[r] *= alpha; o1[r] *= alpha; }
            }
            float ls = 0.f;
            #pragma unroll
            for (int r = 0; r < 16; ++r) {
              float p = fexp2(s[r] - m_run);
              s[r] = p;
              ls += p;
            }
            ls += __shfl_xor(ls, 32, 64);
            l_run += ls;

            unsigned int own[8], rcv[8];
            #pragma unroll
            for (int g = 0; g < 8; ++g)
              own[g] = cvtpk(s[2 * g], s[2 * g + 1]);
            #pragma unroll
            for (int g = 0; g < 8; ++g)
              rcv[g] = (unsigned int)__shfl_xor((int)own[g], 32, 64);

            __builtin_amdgcn_s_setprio(1);
            {
              U4S8 pfv;
              pfv.u4.x = hi ? rcv[2] : own[0];
              pfv.u4.y = hi ? rcv[3] : own[1];
              pfv.u4.z = hi ? own[2] : rcv[0];
              pfv.u4.w = hi ? own[3] : rcv[1];
              int co = ((hk * 4 + hi) ^ (q & 7)) * 8;
              short8 vf0 = *(const short8*)(Vl + q * 64 + co);
              short8 vf1 = *(const short8*)(Vl + (32 + q) * 64 + co);
              o0 = MFMA32(vf0, pfv.v, o0);
              o1 = MFMA32(vf1, pfv.v, o1);
            }
            {
              U4S8 pfv;
              pfv.u4.x = hi ? rcv[6] : own[4];
              pfv.u4.y = hi ? rcv[7] : own[5];
              pfv.u4.z = hi ? own[6] : rcv[4];
              pfv.u4.w = hi ? own[7] : rcv[5];
              int co = ((hk * 4 + 2 + hi) ^ (q & 7)) * 8;
              short8 vf0 = *(const short8*)(Vl + q * 64 + co);
              short8 vf1 = *(const short8*)(Vl + (32 + q) * 64 + co);
              o0 = MFMA32(vf0, pfv.v, o0);
              o1 = MFMA32(vf1, pfv.v, o1);
            }
            __builtin_amdgcn_s_setprio(0);
          }
        }
      }
    }

    __syncthreads();
    cur ^= 1;
  }

  // ---- epilogue: normalize, per-wave LDS transpose (aliases K/V), store ----
  unsigned short* lo = (unsigned short*)smem + (size_t)w * 32 * 72;
  float inv = 1.0f / l_run;
  #pragma unroll
  for (int gg = 0; gg < 8; ++gg) {
    int r = 2 * gg;
    int dl = (r & 3) + 8 * (r >> 2) + 4 * hi;
    unsigned int w0 = (unsigned int)f2bf(o0[r] * inv) | ((unsigned int)f2bf(o0[r + 1] * inv) << 16);
    unsigned int w1 = (unsigned int)f2bf(o1[r] * inv) | ((unsigned int)f2bf(o1[r + 1] * inv) << 16);
    *(unsigned int*)&lo[q * 72 + dl] = w0;
    *(unsigned int*)&lo[q * 72 + 32 + dl] = w1;
  }
  {
    int row = lane >> 1;
    int ch = (lane & 1) * 32;
    uint4 x0 = *(const uint4*)&lo[row * 72 + ch + 0];
    uint4 x1 = *(const uint4*)&lo[row * 72 + ch + 8];
    uint4 x2 = *(const uint4*)&lo[row * 72 + ch + 16];
    uint4 x3 = *(const uint4*)&lo[row * 72 + ch + 24];
    unsigned short* dst = &Ob[(size_t)(b * SEQ + wq0 + row) * (NHEADS * HDIM) + h * HDIM + ch];
    *(uint4*)(dst + 0)  = x0;
    *(uint4*)(dst + 8)  = x1;
    *(uint4*)(dst + 16) = x2;
    *(uint4*)(dst + 24) = x3;
  }
}

// =====================================================================
// launcher
// =====================================================================
extern "C" void kernel_launch(void* const* d_in, const int* in_sizes, int n_in,
                              void* d_out, int out_size, void* d_ws, size_t ws_size,
                              hipStream_t stream) {
  const float* X  = (const float*)d_in[0];
  const float* Wq = (const float*)d_in[1];
  const float* Wk = (const float*)d_in[2];
  const float* Wv = (const float*)d_in[3];
  const float* Wo = (const float*)d_in[4];
  float* out = (float*)d_out;

  char* ws = (char*)d_ws;
  size_t off = 0;
  auto carve = [&](size_t bytes) -> void* {
    void* p = ws + off;
    off += (bytes + 255) & ~(size_t)255;
    return p;
  };
  float* rope_cos = (float*)carve((size_t)SEQ * 32 * 4);
  float* rope_sin = (float*)carve((size_t)SEQ * 32 * 4);
  unsigned short* Xb     = (unsigned short*)carve((size_t)NTOK * HIDDEN * 2);   // reused as Ob
  unsigned short* Wqkv_t = (unsigned short*)carve((size_t)QKVN * HIDDEN * 2);
  unsigned short* Wot    = (unsigned short*)carve((size_t)HIDDEN * HIDDEN * 2);
  unsigned short* QKVb   = (unsigned short*)carve((size_t)NTOK * QKVN * 2);
  unsigned short* Vt     = (unsigned short*)carve((size_t)BATCH * NKV * HDIM * SEQ * 2);
  unsigned short* Ob     = Xb;   // Xb dead after QKV GEMM

  rope_table_kernel<<<dim3(256), dim3(256), 0, stream>>>(rope_cos, rope_sin);
  convert_x_kernel<<<dim3((NTOK * HIDDEN) / (256 * 8)), dim3(256), 0, stream>>>(X, Xb);

  transpose_w_kernel<<<dim3(2048 / 64, HIDDEN / 64), dim3(256), 0, stream>>>(Wq, Wqkv_t, 2048, 0);
  transpose_w_kernel<<<dim3(512 / 64,  HIDDEN / 64), dim3(256), 0, stream>>>(Wk, Wqkv_t, 512, 2048);
  transpose_w_kernel<<<dim3(512 / 64,  HIDDEN / 64), dim3(256), 0, stream>>>(Wv, Wqkv_t, 512, 2560);
  transpose_w_kernel<<<dim3(2048 / 64, HIDDEN / 64), dim3(256), 0, stream>>>(Wo, Wot, 2048, 0);

  // QKV GEMM with fused RoPE (+ Q pre-scale) in the epilogue
  gemm128_kernel<1><<<dim3(QKVN / 128, NTOK / 128), dim3(256), 0, stream>>>(
      Xb, Wqkv_t, QKVb, NTOK, QKVN, HIDDEN, rope_cos, rope_sin);

  v_pack_kernel<<<dim3((NTOK * NKV * HDIM) / 256), dim3(256), 0, stream>>>(QKVb, Vt);

  flash_kernel<<<dim3(SEQ / 128, NHEADS, BATCH), dim3(256), 0, stream>>>(QKVb, Vt, Ob);

  gemm128_kernel<0><<<dim3(HIDDEN / 128, NTOK / 128), dim3(256), 0, stream>>>(
      Ob, Wot, out, NTOK, HIDDEN, HIDDEN, nullptr, nullptr);
}

// Round 13
// 225.973 us; speedup vs baseline: 1.1243x; 1.1243x over previous
//
#include <hip/hip_runtime.h>
#include <cstdint>
#include <cstddef>

// ---------- types ----------
typedef __attribute__((ext_vector_type(8))) short short8;   // 8 bf16 MFMA A/B frag
typedef __attribute__((ext_vector_type(4))) float f32x4;    // 16x16 C/D frag
typedef __attribute__((ext_vector_type(16))) float f32x16;  // 32x32 C/D frag

#define MFMA16(a, b, c) __builtin_amdgcn_mfma_f32_16x16x32_bf16((a), (b), (c), 0, 0, 0)
#define MFMA32(a, b, c) __builtin_amdgcn_mfma_f32_32x32x16_bf16((a), (b), (c), 0, 0, 0)

union F2U { float f; unsigned int u; };
union U4S8 { uint4 u4; unsigned short s[8]; short8 v; };

__device__ __forceinline__ unsigned short f2bf(float f) {
  F2U x; x.f = f;
  unsigned int r = x.u + 0x7fffu + ((x.u >> 16) & 1u);  // RNE
  return (unsigned short)(r >> 16);
}
__device__ __forceinline__ float bf2f(unsigned short s) {
  F2U x; x.u = ((unsigned int)s) << 16;
  return x.f;
}
__device__ __forceinline__ float fexp2(float x) {        // v_exp_f32: D = 2^S0
  float r; asm("v_exp_f32 %0, %1" : "=v"(r) : "v"(x)); return r;
}
__device__ __forceinline__ unsigned int cvtpk(float lo, float hiv) {  // T12
  unsigned int r; asm("v_cvt_pk_bf16_f32 %0, %1, %2" : "=v"(r) : "v"(lo), "v"(hiv)); return r;
}

// ---------- problem constants ----------
#define HIDDEN 2048
#define NHEADS 32
#define NKV 8
#define HDIM 64
#define SEQ 2048
#define BATCH 2
#define NTOK (BATCH * SEQ)   // 4096
#define QKVN 3072            // fused QKV output width (2048 Q | 512 K | 512 V)
#define QSCALE 0.18033688011117309f   // 0.125 * log2(e)

// =====================================================================
// RoPE table: cos/sin [SEQ][32] fp32
// =====================================================================
__global__ __launch_bounds__(256) void rope_table_kernel(float* __restrict__ ct, float* __restrict__ st) {
  int idx = blockIdx.x * 256 + threadIdx.x;     // 0 .. 65535
  int s = idx >> 5;
  int i = idx & 31;
  float invf = expf(-(float)i * (9.210340371976184f / 32.0f));  // 10000^(-i/32)
  float f = (float)s * invf;
  ct[idx] = cosf(f);
  st[idx] = sinf(f);
}

// =====================================================================
// X fp32 -> bf16 (elementwise, vectorized)
// =====================================================================
__global__ __launch_bounds__(256) void convert_x_kernel(const float* __restrict__ X,
                                                        unsigned short* __restrict__ Xb) {
  size_t i = ((size_t)blockIdx.x * 256 + threadIdx.x) * 8;
  float4 a0 = *(const float4*)(X + i);
  float4 a1 = *(const float4*)(X + i + 4);
  U4S8 p;
  p.s[0] = f2bf(a0.x); p.s[1] = f2bf(a0.y); p.s[2] = f2bf(a0.z); p.s[3] = f2bf(a0.w);
  p.s[4] = f2bf(a1.x); p.s[5] = f2bf(a1.y); p.s[6] = f2bf(a1.z); p.s[7] = f2bf(a1.w);
  *(short8*)(Xb + i) = p.v;
}

// =====================================================================
// Weight transpose+convert: W [K=2048][N] fp32 -> Wt[row_off + n][k] bf16
// =====================================================================
__global__ __launch_bounds__(256) void transpose_w_kernel(const float* __restrict__ W,
                                                          unsigned short* __restrict__ Wt,
                                                          int N, int row_off) {
  __shared__ unsigned short lt[64][72];  // [n][k], padded
  const int t = threadIdx.x;
  const int k0 = blockIdx.y * 64, n0 = blockIdx.x * 64;
  #pragma unroll
  for (int p = 0; p < 4; ++p) {
    int kr = p * 16 + (t >> 4);
    int nc = (t & 15) * 4;
    float4 v = *(const float4*)&W[(size_t)(k0 + kr) * N + n0 + nc];
    lt[nc + 0][kr] = f2bf(v.x);
    lt[nc + 1][kr] = f2bf(v.y);
    lt[nc + 2][kr] = f2bf(v.z);
    lt[nc + 3][kr] = f2bf(v.w);
  }
  __syncthreads();
  #pragma unroll
  for (int p = 0; p < 2; ++p) {
    int nr = p * 32 + (t >> 3);
    int kc = (t & 7) * 8;
    *(short8*)&Wt[(size_t)(row_off + n0 + nr) * HIDDEN + k0 + kc] = *(const short8*)&lt[nr][kc];
  }
}

// =====================================================================
// GEMM (m97-class): C[M,N] = A[M,K] @ Bt[N,K]^T, all bf16 operands.
// 128x128 tile, BK=64, 4 waves; global_load_lds w16 + XOR chunk swizzle.
// T1 XCD-aware block swizzle (bijective: nwg % 8 == 0 for both grids).
// MODE 0: fp32 out. MODE 1: bf16 out with FUSED ROPE for QKV.
// =====================================================================
template<int MODE>
__global__ __launch_bounds__(256) void gemm128_kernel(const unsigned short* __restrict__ Ab,
                                                      const unsigned short* __restrict__ Bt,
                                                      void* __restrict__ Cp,
                                                      int M, int N, int K,
                                                      const float* __restrict__ ct,
                                                      const float* __restrict__ st) {
  __shared__ __align__(16) unsigned short lds_a[128][64];
  __shared__ __align__(16) unsigned short lds_b[128][64];

  const int t = threadIdx.x, lane = t & 63, w = t >> 6;
  const int lr = lane & 15, lh = lane >> 4;

  // T1: XCD-aware swizzle — contiguous tile chunk per XCD
  const int orig = blockIdx.y * gridDim.x + blockIdx.x;
  const int nwg  = (int)(gridDim.x * gridDim.y);
  const int cpx  = nwg >> 3;                      // nwg % 8 == 0
  const int swz  = (orig & 7) * cpx + (orig >> 3);
  const int m0 = (swz / (int)gridDim.x) * 128;
  const int n0 = (swz % (int)gridDim.x) * 128;

  const int wr = (w >> 1) * 64, wc = (w & 1) * 64;

  f32x4 acc[4][4] = {};

  for (int k0 = 0; k0 < K; k0 += 64) {
    __syncthreads();
    #pragma unroll
    for (int c = 0; c < 4; ++c) {
      int row = w * 32 + c * 8 + (lane >> 3);
      int cks = (lane & 7) ^ (row & 7);
      __builtin_amdgcn_global_load_lds(
          (const __attribute__((address_space(1))) unsigned int*)(Ab + (size_t)(m0 + row) * K + k0 + cks * 8),
          (__attribute__((address_space(3))) unsigned int*)&lds_a[w * 32 + c * 8][0], 16, 0, 0);
      __builtin_amdgcn_global_load_lds(
          (const __attribute__((address_space(1))) unsigned int*)(Bt + (size_t)(n0 + row) * K + k0 + cks * 8),
          (__attribute__((address_space(3))) unsigned int*)&lds_b[w * 32 + c * 8][0], 16, 0, 0);
    }
    __syncthreads();

    #pragma unroll
    for (int kk = 0; kk < 2; ++kk) {
      short8 af[4], bf[4];
      #pragma unroll
      for (int i = 0; i < 4; ++i) {
        int row = wr + i * 16 + lr;
        af[i] = *(const short8*)((const char*)&lds_a[0][0] + row * 128 + (((kk * 4 + lh) ^ (row & 7)) * 16));
      }
      #pragma unroll
      for (int j = 0; j < 4; ++j) {
        int row = wc + j * 16 + lr;
        bf[j] = *(const short8*)((const char*)&lds_b[0][0] + row * 128 + (((kk * 4 + lh) ^ (row & 7)) * 16));
      }
      #pragma unroll
      for (int i = 0; i < 4; ++i)
        #pragma unroll
        for (int j = 0; j < 4; ++j)
          acc[i][j] = MFMA16(af[i], bf[j], acc[i][j]);
    }
  }

  if constexpr (MODE == 0) {
    #pragma unroll
    for (int i = 0; i < 4; ++i)
      #pragma unroll
      for (int j = 0; j < 4; ++j)
        #pragma unroll
        for (int r = 0; r < 4; ++r) {
          int row = m0 + wr + i * 16 + lh * 4 + r;
          int col = n0 + wc + j * 16 + lr;
          ((float*)Cp)[(size_t)row * N + col] = acc[i][j][r];
        }
  } else {
    const bool isV = (n0 >= 2560);
    const bool isQ = (n0 < 2048);
    #pragma unroll
    for (int i = 0; i < 4; ++i)
      #pragma unroll
      for (int r = 0; r < 4; ++r) {
        int row = m0 + wr + i * 16 + lh * 4 + r;
        int s_tok = row & (SEQ - 1);
        float c0 = 0.f, s0 = 0.f, c1 = 0.f, s1 = 0.f;
        if (!isV) {
          c0 = ct[s_tok * 32 + lr];      s0 = st[s_tok * 32 + lr];
          c1 = ct[s_tok * 32 + 16 + lr]; s1 = st[s_tok * 32 + 16 + lr];
        }
        #pragma unroll
        for (int j = 0; j < 4; ++j) {
          int col = n0 + wc + j * 16 + lr;
          float v = acc[i][j][r];
          float o;
          if (isV) {
            o = v;
          } else {
            float p = acc[i][j ^ 2][r];          // partner col^32 (const idx)
            float cc = (j & 1) ? c1 : c0;
            float ss = (j & 1) ? s1 : s0;
            o = v * cc + ((j & 2) ? p : -p) * ss;  // rotate_half sign
            if (isQ) o *= QSCALE;
          }
          ((unsigned short*)Cp)[(size_t)row * N + col] = f2bf(o);
        }
      }
  }
}

// =====================================================================
// V pack/transpose: QKVb cols 2560.. -> Vt [B][KV][64][S] bf16
// =====================================================================
__global__ __launch_bounds__(256) void v_pack_kernel(const unsigned short* __restrict__ QKV,
                                                     unsigned short* __restrict__ Vt) {
  int idx = blockIdx.x * 256 + threadIdx.x;
  int m = idx >> 9;
  int c = idx & 511;
  int b = m >> 11, s = m & 2047;
  int kv = c >> 6, d = c & 63;
  Vt[(((size_t)(b * NKV + kv)) * HDIM + d) * SEQ + s] = QKV[(size_t)m * QKVN + 2560 + c];
}

// =====================================================================
// Flash attention, BALANCED-PAIR grid: grid.x = 8; block bx processes
// Q-tile qb = 15-bx (heavy) then qb = bx (light) — every block does
// exactly 34 tile-iterations, so occupancy stays flat (no causal tail).
// Inner structure = R11's proven kernel: 4 waves x 32 q-rows, KVBLK=64
// cooperative dbuf LDS staging of K and V, swapped QK^T 32x32 MFMA, two
// sequential 32-key halves, exp2 softmax, T12 cvt_pk, T13 defer-max.
// All P selects compile-time-constant (rule #20).
// =====================================================================
#define KVBLK 64

__global__ __launch_bounds__(256, 4) void flash_kernel(const unsigned short* __restrict__ QKV,
                                                       const unsigned short* __restrict__ Vt,
                                                       unsigned short* __restrict__ Ob) {
  const int bx = blockIdx.x;     // 0..7 (pair index)
  const int h = blockIdx.y;
  const int b = blockIdx.z;
  const int kv = h >> 2;
  const int t = threadIdx.x;
  const int lane = t & 63;
  const int w = t >> 6;          // 0..3
  const int q = lane & 31;
  const int hi = lane >> 5;

  // [0,16384): K dbuf [2][64][64] bf16 ; [16384,32768): V dbuf [2][64][64]
  // epilogue: region reused as per-wave transpose buffers [4][32*72]
  __shared__ __align__(16) char smem[32768];
  unsigned short* Klds = (unsigned short*)smem;
  unsigned short* Vlds = (unsigned short*)(smem + 16384);

  const unsigned short* Kg = QKV + (size_t)b * SEQ * QKVN + 2048 + kv * 64;
  const unsigned short* Vg = Vt + ((size_t)(b * NKV + kv)) * HDIM * SEQ;
  const unsigned short* Qh = QKV + (size_t)b * SEQ * QKVN + h * 64;

  // staging: wave w covers rows [w*16, w*16+16), two 8-row groups.
  const int srow = w * 16 + (lane >> 3);
  const int scks = (lane & 7) ^ (srow & 7);      // (srow+8)&7 == srow&7
  const unsigned short* Ksrc = Kg + (size_t)srow * QKVN + scks * 8;   // + kt0*QKVN
  const unsigned short* Vsrc = Vg + (size_t)srow * SEQ + scks * 8;    // + kt0

  #define STAGE_KV(buf, kt0)                                                              \
    do {                                                                                  \
      __builtin_amdgcn_global_load_lds(                                                   \
          (const __attribute__((address_space(1))) unsigned int*)(Ksrc + (size_t)(kt0) * QKVN), \
          (__attribute__((address_space(3))) unsigned int*)(Klds + (buf) * 4096 + w * 1024), 16, 0, 0); \
      __builtin_amdgcn_global_load_lds(                                                   \
          (const __attribute__((address_space(1))) unsigned int*)(Ksrc + (size_t)(kt0) * QKVN + 8 * QKVN), \
          (__attribute__((address_space(3))) unsigned int*)(Klds + (buf) * 4096 + w * 1024 + 512), 16, 0, 0); \
      __builtin_amdgcn_global_load_lds(                                                   \
          (const __attribute__((address_space(1))) unsigned int*)(Vsrc + (kt0)),          \
          (__attribute__((address_space(3))) unsigned int*)(Vlds + (buf) * 4096 + w * 1024), 16, 0, 0); \
      __builtin_amdgcn_global_load_lds(                                                   \
          (const __attribute__((address_space(1))) unsigned int*)(Vsrc + (kt0) + 8 * SEQ), \
          (__attribute__((address_space(3))) unsigned int*)(Vlds + (buf) * 4096 + w * 1024 + 512), 16, 0, 0); \
    } while (0)

  #pragma unroll 1
  for (int seg = 0; seg < 2; ++seg) {
    const int qb = seg ? bx : (15 - bx);
    const int wq0 = qb * 128 + w * 32;

    // Q B-frags (pre-scaled by 0.125*log2e in GEMM epilogue)
    short8 qf[4];
    #pragma unroll
    for (int f = 0; f < 4; ++f)
      qf[f] = *(const short8*)&Qh[(size_t)(wq0 + q) * QKVN + f * 16 + hi * 8];

    f32x16 o0 = {}, o1 = {};
    float m_run = -1e30f, l_run = 0.f;

    const int nt_blk = qb * 2 + 2;            // tiles staged by the block
    const int nt_w   = qb * 2 + (w >> 1) + 1; // tiles this wave computes

    __syncthreads();   // protect LDS from previous segment's epilogue reads
    STAGE_KV(0, 0);
    __syncthreads();
    int cur = 0;

    for (int tt = 0; tt < nt_blk; ++tt) {
      if (tt + 1 < nt_blk) STAGE_KV(cur ^ 1, (tt + 1) * KVBLK);

      if (tt < nt_w) {
        const int kt0 = tt * KVBLK;
        const unsigned short* Kt = Klds + cur * 4096;
        const unsigned short* Vl = Vlds + cur * 4096;

        #pragma unroll
        for (int hk = 0; hk < 2; ++hk) {
          const int kbase = kt0 + hk * 32;
          if (kbase <= wq0 + 31) {          // wave-uniform: not fully masked
            // ---- S^T = K Q^T (one 32-key half), scores in log2 domain ----
            f32x16 s = {};
            __builtin_amdgcn_s_setprio(1);
            #pragma unroll
            for (int f = 0; f < 4; ++f) {
              short8 kf = *(const short8*)(Kt + (hk * 32 + q) * 64 + (((f * 2 + hi) ^ (q & 7)) * 8));
              s = MFMA32(kf, qf[f], s);
            }
            __builtin_amdgcn_s_setprio(0);

            // ---- causal mask (diagonal half only) ----
            if (kbase + 31 > wq0) {
              #pragma unroll
              for (int r = 0; r < 16; ++r) {
                int kl = (r & 3) + 8 * (r >> 2) + 4 * hi;
                if (kbase + kl > wq0 + q) s[r] = -1e30f;
              }
            }

            // ---- row max ----
            float mt = -1e30f;
            #pragma unroll
            for (int r = 0; r < 16; ++r) mt = fmaxf(mt, s[r]);
            mt = fmaxf(mt, __shfl_xor(mt, 32, 64));

            // ---- online softmax (exp2 domain), defer-max THR=11 ----
            const bool resc = __any(mt > m_run + 11.0f);
            if (resc) {
              float mn = fmaxf(m_run, mt);
              float alpha = fexp2(m_run - mn);
              m_run = mn;
              l_run *= alpha;
              #pragma unroll
              for (int r = 0; r < 16; ++r) { o0[r] *= alpha; o1[r] *= alpha; }
            }
            float ls = 0.f;
            #pragma unroll
            for (int r = 0; r < 16; ++r) {
              float p = fexp2(s[r] - m_run);
              s[r] = p;
              ls += p;
            }
            ls += __shfl_xor(ls, 32, 64);
            l_run += ls;

            // ---- pack P -> bf16 pairs (cvt_pk), exchange halves ----
            unsigned int own[8], rcv[8];
            #pragma unroll
            for (int g = 0; g < 8; ++g)
              own[g] = cvtpk(s[2 * g], s[2 * g + 1]);
            #pragma unroll
            for (int g = 0; g < 8; ++g)
              rcv[g] = (unsigned int)__shfl_xor((int)own[g], 32, 64);

            // ---- P^T frags + PV (constant indices only — rule #20) ----
            __builtin_amdgcn_s_setprio(1);
            {
              U4S8 pfv;
              pfv.u4.x = hi ? rcv[2] : own[0];
              pfv.u4.y = hi ? rcv[3] : own[1];
              pfv.u4.z = hi ? own[2] : rcv[0];
              pfv.u4.w = hi ? own[3] : rcv[1];
              int co = ((hk * 4 + hi) ^ (q & 7)) * 8;
              short8 vf0 = *(const short8*)(Vl + q * 64 + co);
              short8 vf1 = *(const short8*)(Vl + (32 + q) * 64 + co);
              o0 = MFMA32(vf0, pfv.v, o0);
              o1 = MFMA32(vf1, pfv.v, o1);
            }
            {
              U4S8 pfv;
              pfv.u4.x = hi ? rcv[6] : own[4];
              pfv.u4.y = hi ? rcv[7] : own[5];
              pfv.u4.z = hi ? own[6] : rcv[4];
              pfv.u4.w = hi ? own[7] : rcv[5];
              int co = ((hk * 4 + 2 + hi) ^ (q & 7)) * 8;
              short8 vf0 = *(const short8*)(Vl + q * 64 + co);
              short8 vf1 = *(const short8*)(Vl + (32 + q) * 64 + co);
              o0 = MFMA32(vf0, pfv.v, o0);
              o1 = MFMA32(vf1, pfv.v, o1);
            }
            __builtin_amdgcn_s_setprio(0);
          }
        }
      }

      __syncthreads();
      cur ^= 1;
    }

    // ---- epilogue: normalize, per-wave LDS transpose (aliases K/V), store ----
    unsigned short* lo = (unsigned short*)smem + (size_t)w * 32 * 72;
    float inv = 1.0f / l_run;
    #pragma unroll
    for (int gg = 0; gg < 8; ++gg) {
      int r = 2 * gg;
      int dl = (r & 3) + 8 * (r >> 2) + 4 * hi;
      unsigned int w0 = (unsigned int)f2bf(o0[r] * inv) | ((unsigned int)f2bf(o0[r + 1] * inv) << 16);
      unsigned int w1 = (unsigned int)f2bf(o1[r] * inv) | ((unsigned int)f2bf(o1[r + 1] * inv) << 16);
      *(unsigned int*)&lo[q * 72 + dl] = w0;
      *(unsigned int*)&lo[q * 72 + 32 + dl] = w1;
    }
    {
      int row = lane >> 1;
      int ch = (lane & 1) * 32;
      uint4 x0 = *(const uint4*)&lo[row * 72 + ch + 0];
      uint4 x1 = *(const uint4*)&lo[row * 72 + ch + 8];
      uint4 x2 = *(const uint4*)&lo[row * 72 + ch + 16];
      uint4 x3 = *(const uint4*)&lo[row * 72 + ch + 24];
      unsigned short* dst = &Ob[(size_t)(b * SEQ + wq0 + row) * (NHEADS * HDIM) + h * HDIM + ch];
      *(uint4*)(dst + 0)  = x0;
      *(uint4*)(dst + 8)  = x1;
      *(uint4*)(dst + 16) = x2;
      *(uint4*)(dst + 24) = x3;
    }
  }
}

// =====================================================================
// launcher
// =====================================================================
extern "C" void kernel_launch(void* const* d_in, const int* in_sizes, int n_in,
                              void* d_out, int out_size, void* d_ws, size_t ws_size,
                              hipStream_t stream) {
  const float* X  = (const float*)d_in[0];
  const float* Wq = (const float*)d_in[1];
  const float* Wk = (const float*)d_in[2];
  const float* Wv = (const float*)d_in[3];
  const float* Wo = (const float*)d_in[4];
  float* out = (float*)d_out;

  char* ws = (char*)d_ws;
  size_t off = 0;
  auto carve = [&](size_t bytes) -> void* {
    void* p = ws + off;
    off += (bytes + 255) & ~(size_t)255;
    return p;
  };
  float* rope_cos = (float*)carve((size_t)SEQ * 32 * 4);
  float* rope_sin = (float*)carve((size_t)SEQ * 32 * 4);
  unsigned short* Xb     = (unsigned short*)carve((size_t)NTOK * HIDDEN * 2);   // reused as Ob
  unsigned short* Wqkv_t = (unsigned short*)carve((size_t)QKVN * HIDDEN * 2);
  unsigned short* Wot    = (unsigned short*)carve((size_t)HIDDEN * HIDDEN * 2);
  unsigned short* QKVb   = (unsigned short*)carve((size_t)NTOK * QKVN * 2);
  unsigned short* Vt     = (unsigned short*)carve((size_t)BATCH * NKV * HDIM * SEQ * 2);
  unsigned short* Ob     = Xb;   // Xb dead after QKV GEMM

  rope_table_kernel<<<dim3(256), dim3(256), 0, stream>>>(rope_cos, rope_sin);
  convert_x_kernel<<<dim3((NTOK * HIDDEN) / (256 * 8)), dim3(256), 0, stream>>>(X, Xb);

  transpose_w_kernel<<<dim3(2048 / 64, HIDDEN / 64), dim3(256), 0, stream>>>(Wq, Wqkv_t, 2048, 0);
  transpose_w_kernel<<<dim3(512 / 64,  HIDDEN / 64), dim3(256), 0, stream>>>(Wk, Wqkv_t, 512, 2048);
  transpose_w_kernel<<<dim3(512 / 64,  HIDDEN / 64), dim3(256), 0, stream>>>(Wv, Wqkv_t, 512, 2560);
  transpose_w_kernel<<<dim3(2048 / 64, HIDDEN / 64), dim3(256), 0, stream>>>(Wo, Wot, 2048, 0);

  // QKV GEMM with fused RoPE (+ Q pre-scale) in the epilogue
  gemm128_kernel<1><<<dim3(QKVN / 128, NTOK / 128), dim3(256), 0, stream>>>(
      Xb, Wqkv_t, QKVb, NTOK, QKVN, HIDDEN, rope_cos, rope_sin);

  v_pack_kernel<<<dim3((NTOK * NKV * HDIM) / 256), dim3(256), 0, stream>>>(QKVb, Vt);

  flash_kernel<<<dim3(8, NHEADS, BATCH), dim3(256), 0, stream>>>(QKVb, Vt, Ob);

  gemm128_kernel<0><<<dim3(HIDDEN / 128, NTOK / 128), dim3(256), 0, stream>>>(
      Ob, Wot, out, NTOK, HIDDEN, HIDDEN, nullptr, nullptr);
}

// Round 14
// 222.340 us; speedup vs baseline: 1.1427x; 1.0163x over previous
//
#include <hip/hip_runtime.h>
#include <cstdint>
#include <cstddef>

// ---------- types ----------
typedef __attribute__((ext_vector_type(8))) short short8;   // 8 bf16 MFMA A/B frag
typedef __attribute__((ext_vector_type(4))) float f32x4;    // 16x16 C/D frag
typedef __attribute__((ext_vector_type(16))) float f32x16;  // 32x32 C/D frag

#define MFMA16(a, b, c) __builtin_amdgcn_mfma_f32_16x16x32_bf16((a), (b), (c), 0, 0, 0)
#define MFMA32(a, b, c) __builtin_amdgcn_mfma_f32_32x32x16_bf16((a), (b), (c), 0, 0, 0)

union F2U { float f; unsigned int u; };
union U4S8 { uint4 u4; unsigned short s[8]; short8 v; };

__device__ __forceinline__ unsigned short f2bf(float f) {
  F2U x; x.f = f;
  unsigned int r = x.u + 0x7fffu + ((x.u >> 16) & 1u);  // RNE
  return (unsigned short)(r >> 16);
}
__device__ __forceinline__ float bf2f(unsigned short s) {
  F2U x; x.u = ((unsigned int)s) << 16;
  return x.f;
}
__device__ __forceinline__ float fexp2(float x) {        // v_exp_f32: D = 2^S0
  float r; asm("v_exp_f32 %0, %1" : "=v"(r) : "v"(x)); return r;
}
__device__ __forceinline__ unsigned int cvtpk(float lo, float hiv) {  // T12
  unsigned int r; asm("v_cvt_pk_bf16_f32 %0, %1, %2" : "=v"(r) : "v"(lo), "v"(hiv)); return r;
}

// ---------- problem constants ----------
#define HIDDEN 2048
#define NHEADS 32
#define NKV 8
#define HDIM 64
#define SEQ 2048
#define BATCH 2
#define NTOK (BATCH * SEQ)   // 4096
#define QKVN 3072            // fused QKV output width (2048 Q | 512 K | 512 V)
#define QSCALE 0.18033688011117309f   // 0.125 * log2(e)

// =====================================================================
// RoPE table: cos/sin [SEQ][32] fp32
// =====================================================================
__global__ __launch_bounds__(256) void rope_table_kernel(float* __restrict__ ct, float* __restrict__ st) {
  int idx = blockIdx.x * 256 + threadIdx.x;     // 0 .. 65535
  int s = idx >> 5;
  int i = idx & 31;
  float invf = expf(-(float)i * (9.210340371976184f / 32.0f));  // 10000^(-i/32)
  float f = (float)s * invf;
  ct[idx] = cosf(f);
  st[idx] = sinf(f);
}

// =====================================================================
// X fp32 -> bf16 (elementwise, vectorized)
// =====================================================================
__global__ __launch_bounds__(256) void convert_x_kernel(const float* __restrict__ X,
                                                        unsigned short* __restrict__ Xb) {
  size_t i = ((size_t)blockIdx.x * 256 + threadIdx.x) * 8;
  float4 a0 = *(const float4*)(X + i);
  float4 a1 = *(const float4*)(X + i + 4);
  U4S8 p;
  p.s[0] = f2bf(a0.x); p.s[1] = f2bf(a0.y); p.s[2] = f2bf(a0.z); p.s[3] = f2bf(a0.w);
  p.s[4] = f2bf(a1.x); p.s[5] = f2bf(a1.y); p.s[6] = f2bf(a1.z); p.s[7] = f2bf(a1.w);
  *(short8*)(Xb + i) = p.v;
}

// =====================================================================
// Weight transpose+convert: W [K=2048][N] fp32 -> Wt[row_off + n][k] bf16
// =====================================================================
__global__ __launch_bounds__(256) void transpose_w_kernel(const float* __restrict__ W,
                                                          unsigned short* __restrict__ Wt,
                                                          int N, int row_off) {
  __shared__ unsigned short lt[64][72];  // [n][k], padded
  const int t = threadIdx.x;
  const int k0 = blockIdx.y * 64, n0 = blockIdx.x * 64;
  #pragma unroll
  for (int p = 0; p < 4; ++p) {
    int kr = p * 16 + (t >> 4);
    int nc = (t & 15) * 4;
    float4 v = *(const float4*)&W[(size_t)(k0 + kr) * N + n0 + nc];
    lt[nc + 0][kr] = f2bf(v.x);
    lt[nc + 1][kr] = f2bf(v.y);
    lt[nc + 2][kr] = f2bf(v.z);
    lt[nc + 3][kr] = f2bf(v.w);
  }
  __syncthreads();
  #pragma unroll
  for (int p = 0; p < 2; ++p) {
    int nr = p * 32 + (t >> 3);
    int kc = (t & 7) * 8;
    *(short8*)&Wt[(size_t)(row_off + n0 + nr) * HIDDEN + k0 + kc] = *(const short8*)&lt[nr][kc];
  }
}

// =====================================================================
// GEMM (m97-class): C[M,N] = A[M,K] @ Bt[N,K]^T, all bf16 operands.
// 128x128 tile, BK=64, 4 waves; global_load_lds w16 + XOR chunk swizzle.
// T1 XCD-aware block swizzle (bijective: nwg % 8 == 0 for both grids).
// MODE 0: fp32 out. MODE 1: bf16 out with FUSED ROPE for QKV.
// =====================================================================
template<int MODE>
__global__ __launch_bounds__(256) void gemm128_kernel(const unsigned short* __restrict__ Ab,
                                                      const unsigned short* __restrict__ Bt,
                                                      void* __restrict__ Cp,
                                                      int M, int N, int K,
                                                      const float* __restrict__ ct,
                                                      const float* __restrict__ st) {
  __shared__ __align__(16) unsigned short lds_a[128][64];
  __shared__ __align__(16) unsigned short lds_b[128][64];

  const int t = threadIdx.x, lane = t & 63, w = t >> 6;
  const int lr = lane & 15, lh = lane >> 4;

  // T1: XCD-aware swizzle — contiguous tile chunk per XCD
  const int orig = blockIdx.y * gridDim.x + blockIdx.x;
  const int nwg  = (int)(gridDim.x * gridDim.y);
  const int cpx  = nwg >> 3;                      // nwg % 8 == 0
  const int swz  = (orig & 7) * cpx + (orig >> 3);
  const int m0 = (swz / (int)gridDim.x) * 128;
  const int n0 = (swz % (int)gridDim.x) * 128;

  const int wr = (w >> 1) * 64, wc = (w & 1) * 64;

  f32x4 acc[4][4] = {};

  for (int k0 = 0; k0 < K; k0 += 64) {
    __syncthreads();
    #pragma unroll
    for (int c = 0; c < 4; ++c) {
      int row = w * 32 + c * 8 + (lane >> 3);
      int cks = (lane & 7) ^ (row & 7);
      __builtin_amdgcn_global_load_lds(
          (const __attribute__((address_space(1))) unsigned int*)(Ab + (size_t)(m0 + row) * K + k0 + cks * 8),
          (__attribute__((address_space(3))) unsigned int*)&lds_a[w * 32 + c * 8][0], 16, 0, 0);
      __builtin_amdgcn_global_load_lds(
          (const __attribute__((address_space(1))) unsigned int*)(Bt + (size_t)(n0 + row) * K + k0 + cks * 8),
          (__attribute__((address_space(3))) unsigned int*)&lds_b[w * 32 + c * 8][0], 16, 0, 0);
    }
    __syncthreads();

    #pragma unroll
    for (int kk = 0; kk < 2; ++kk) {
      short8 af[4], bf[4];
      #pragma unroll
      for (int i = 0; i < 4; ++i) {
        int row = wr + i * 16 + lr;
        af[i] = *(const short8*)((const char*)&lds_a[0][0] + row * 128 + (((kk * 4 + lh) ^ (row & 7)) * 16));
      }
      #pragma unroll
      for (int j = 0; j < 4; ++j) {
        int row = wc + j * 16 + lr;
        bf[j] = *(const short8*)((const char*)&lds_b[0][0] + row * 128 + (((kk * 4 + lh) ^ (row & 7)) * 16));
      }
      #pragma unroll
      for (int i = 0; i < 4; ++i)
        #pragma unroll
        for (int j = 0; j < 4; ++j)
          acc[i][j] = MFMA16(af[i], bf[j], acc[i][j]);
    }
  }

  if constexpr (MODE == 0) {
    #pragma unroll
    for (int i = 0; i < 4; ++i)
      #pragma unroll
      for (int j = 0; j < 4; ++j)
        #pragma unroll
        for (int r = 0; r < 4; ++r) {
          int row = m0 + wr + i * 16 + lh * 4 + r;
          int col = n0 + wc + j * 16 + lr;
          ((float*)Cp)[(size_t)row * N + col] = acc[i][j][r];
        }
  } else {
    const bool isV = (n0 >= 2560);
    const bool isQ = (n0 < 2048);
    #pragma unroll
    for (int i = 0; i < 4; ++i)
      #pragma unroll
      for (int r = 0; r < 4; ++r) {
        int row = m0 + wr + i * 16 + lh * 4 + r;
        int s_tok = row & (SEQ - 1);
        float c0 = 0.f, s0 = 0.f, c1 = 0.f, s1 = 0.f;
        if (!isV) {
          c0 = ct[s_tok * 32 + lr];      s0 = st[s_tok * 32 + lr];
          c1 = ct[s_tok * 32 + 16 + lr]; s1 = st[s_tok * 32 + 16 + lr];
        }
        #pragma unroll
        for (int j = 0; j < 4; ++j) {
          int col = n0 + wc + j * 16 + lr;
          float v = acc[i][j][r];
          float o;
          if (isV) {
            o = v;
          } else {
            float p = acc[i][j ^ 2][r];          // partner col^32 (const idx)
            float cc = (j & 1) ? c1 : c0;
            float ss = (j & 1) ? s1 : s0;
            o = v * cc + ((j & 2) ? p : -p) * ss;  // rotate_half sign
            if (isQ) o *= QSCALE;
          }
          ((unsigned short*)Cp)[(size_t)row * N + col] = f2bf(o);
        }
      }
  }
}

// =====================================================================
// V pack/transpose: QKVb cols 2560.. -> Vt [B][KV][64][S] bf16
// =====================================================================
__global__ __launch_bounds__(256) void v_pack_kernel(const unsigned short* __restrict__ QKV,
                                                     unsigned short* __restrict__ Vt) {
  int idx = blockIdx.x * 256 + threadIdx.x;
  int m = idx >> 9;
  int c = idx & 511;
  int b = m >> 11, s = m & 2047;
  int kv = c >> 6, d = c & 63;
  Vt[(((size_t)(b * NKV + kv)) * HDIM + d) * SEQ + s] = QKV[(size_t)m * QKVN + 2560 + c];
}

// =====================================================================
// Flash attention, SPLIT-K wave pairs + balanced-pair grid.
// 8 waves (512 thr): pair p = w>>1 owns q-rows [p*32,p*32+32); wave
// kh = w&1 processes key-half kh of every KVBLK=64 tile with private
// (m,l,O); fp32 LDS merge per pair at segment end. Grid.x=8: block bx
// does qb=15-bx then qb=bx (uniform work). Staging volume and MFMA
// count unchanged vs R13 — only wave-parallelism doubles (16 waves/CU).
// exp2 softmax, T12 cvt_pk, T13 defer-max, rule #20 discipline.
// =====================================================================
#define KVBLK 64

__global__ __launch_bounds__(512, 4) void flash_kernel(const unsigned short* __restrict__ QKV,
                                                       const unsigned short* __restrict__ Vt,
                                                       unsigned short* __restrict__ Ob) {
  const int bx = blockIdx.x;     // 0..7 (pair index)
  const int h = blockIdx.y;
  const int b = blockIdx.z;
  const int kv = h >> 2;
  const int t = threadIdx.x;
  const int lane = t & 63;
  const int w = t >> 6;          // 0..7
  const int p = w >> 1;          // q-row group 0..3
  const int kh = w & 1;          // key half 0/1
  const int q = lane & 31;
  const int hi = lane >> 5;

  // [0,16384): K dbuf 2x[64][64] bf16 ; [16384,32768): V dbuf.
  // After staging dead: o-merge area [0,32768) = 4 pairs x 8 KB;
  // ml area [32768,34816). Epilogue lo regions [0,18432) after sync.
  __shared__ __align__(16) char smem[34816];
  unsigned short* Klds = (unsigned short*)smem;
  unsigned short* Vlds = (unsigned short*)(smem + 16384);
  float* mlArea = (float*)(smem + 32768);   // [pair][kh][q][{m,l}]

  const unsigned short* Kg = QKV + (size_t)b * SEQ * QKVN + 2048 + kv * 64;
  const unsigned short* Vg = Vt + ((size_t)(b * NKV + kv)) * HDIM * SEQ;
  const unsigned short* Qh = QKV + (size_t)b * SEQ * QKVN + h * 64;

  // staging: wave w covers rows [w*8, w*8+8); 1 load per operand per tile
  const int srow = w * 8 + (lane >> 3);
  const int scks = (lane & 7) ^ (srow & 7);
  const unsigned short* Ksrc = Kg + (size_t)srow * QKVN + scks * 8;   // + kt0*QKVN
  const unsigned short* Vsrc = Vg + (size_t)srow * SEQ + scks * 8;    // + kt0

  #define STAGE_KV(buf, kt0)                                                              \
    do {                                                                                  \
      __builtin_amdgcn_global_load_lds(                                                   \
          (const __attribute__((address_space(1))) unsigned int*)(Ksrc + (size_t)(kt0) * QKVN), \
          (__attribute__((address_space(3))) unsigned int*)(Klds + (buf) * 4096 + w * 512), 16, 0, 0); \
      __builtin_amdgcn_global_load_lds(                                                   \
          (const __attribute__((address_space(1))) unsigned int*)(Vsrc + (kt0)),          \
          (__attribute__((address_space(3))) unsigned int*)(Vlds + (buf) * 4096 + w * 512), 16, 0, 0); \
    } while (0)

  #pragma unroll 1
  for (int seg = 0; seg < 2; ++seg) {
    const int qb = seg ? bx : (15 - bx);
    const int wq0 = qb * 128 + p * 32;

    // Q B-frags (pre-scaled by 0.125*log2e in GEMM epilogue)
    short8 qf[4];
    #pragma unroll
    for (int f = 0; f < 4; ++f)
      qf[f] = *(const short8*)&Qh[(size_t)(wq0 + q) * QKVN + f * 16 + hi * 8];

    f32x16 o0 = {}, o1 = {};
    float m_run = -1e30f, l_run = 0.f;

    const int nt_blk = qb * 2 + 2;   // tiles staged by the block

    __syncthreads();   // protect LDS from previous segment's epilogue
    STAGE_KV(0, 0);
    __syncthreads();
    int cur = 0;

    for (int tt = 0; tt < nt_blk; ++tt) {
      if (tt + 1 < nt_blk) STAGE_KV(cur ^ 1, (tt + 1) * KVBLK);

      const int kbase = tt * KVBLK + kh * 32;
      if (kbase <= wq0 + 31) {       // wave-uniform: this half has live keys
        const unsigned short* Kt = Klds + cur * 4096;
        const unsigned short* Vl = Vlds + cur * 4096;

        // ---- S^T = K Q^T (this wave's 32-key half), log2 domain ----
        f32x16 s = {};
        __builtin_amdgcn_s_setprio(1);
        #pragma unroll
        for (int f = 0; f < 4; ++f) {
          short8 kf = *(const short8*)(Kt + (kh * 32 + q) * 64 + (((f * 2 + hi) ^ (q & 7)) * 8));
          s = MFMA32(kf, qf[f], s);
        }
        __builtin_amdgcn_s_setprio(0);

        // ---- causal mask (diagonal half only) ----
        if (kbase + 31 > wq0) {
          #pragma unroll
          for (int r = 0; r < 16; ++r) {
            int kl = (r & 3) + 8 * (r >> 2) + 4 * hi;
            if (kbase + kl > wq0 + q) s[r] = -1e30f;
          }
        }

        // ---- row max ----
        float mt = -1e30f;
        #pragma unroll
        for (int r = 0; r < 16; ++r) mt = fmaxf(mt, s[r]);
        mt = fmaxf(mt, __shfl_xor(mt, 32, 64));

        // ---- online softmax (exp2 domain), defer-max THR=11 ----
        const bool resc = __any(mt > m_run + 11.0f);
        if (resc) {
          float mn = fmaxf(m_run, mt);
          float alpha = fexp2(m_run - mn);
          m_run = mn;
          l_run *= alpha;
          #pragma unroll
          for (int r = 0; r < 16; ++r) { o0[r] *= alpha; o1[r] *= alpha; }
        }
        float ls = 0.f;
        #pragma unroll
        for (int r = 0; r < 16; ++r) {
          float pp = fexp2(s[r] - m_run);
          s[r] = pp;
          ls += pp;
        }
        ls += __shfl_xor(ls, 32, 64);
        l_run += ls;

        // ---- pack P -> bf16 pairs (cvt_pk), exchange halves ----
        unsigned int own[8], rcv[8];
        #pragma unroll
        for (int g = 0; g < 8; ++g)
          own[g] = cvtpk(s[2 * g], s[2 * g + 1]);
        #pragma unroll
        for (int g = 0; g < 8; ++g)
          rcv[g] = (unsigned int)__shfl_xor((int)own[g], 32, 64);

        // ---- P^T frags + PV (constant indices only — rule #20) ----
        __builtin_amdgcn_s_setprio(1);
        {
          U4S8 pfv;
          pfv.u4.x = hi ? rcv[2] : own[0];
          pfv.u4.y = hi ? rcv[3] : own[1];
          pfv.u4.z = hi ? own[2] : rcv[0];
          pfv.u4.w = hi ? own[3] : rcv[1];
          int co = ((kh * 4 + hi) ^ (q & 7)) * 8;
          short8 vf0 = *(const short8*)(Vl + q * 64 + co);
          short8 vf1 = *(const short8*)(Vl + (32 + q) * 64 + co);
          o0 = MFMA32(vf0, pfv.v, o0);
          o1 = MFMA32(vf1, pfv.v, o1);
        }
        {
          U4S8 pfv;
          pfv.u4.x = hi ? rcv[6] : own[4];
          pfv.u4.y = hi ? rcv[7] : own[5];
          pfv.u4.z = hi ? own[6] : rcv[4];
          pfv.u4.w = hi ? own[7] : rcv[5];
          int co = ((kh * 4 + 2 + hi) ^ (q & 7)) * 8;
          short8 vf0 = *(const short8*)(Vl + q * 64 + co);
          short8 vf1 = *(const short8*)(Vl + (32 + q) * 64 + co);
          o0 = MFMA32(vf0, pfv.v, o0);
          o1 = MFMA32(vf1, pfv.v, o1);
        }
        __builtin_amdgcn_s_setprio(0);
      }

      __syncthreads();
      cur ^= 1;
    }

    // ============ cross-wave (split-K) merge, per pair ============
    if (hi == 0) {
      mlArea[(w * 32 + q) * 2 + 0] = m_run;
      mlArea[(w * 32 + q) * 2 + 1] = l_run;
    }
    __syncthreads();
    const int wo = p * 2 + (kh ^ 1);           // partner wave index
    float m_oth = mlArea[(wo * 32 + q) * 2 + 0];
    float l_oth = mlArea[(wo * 32 + q) * 2 + 1];
    float m_tot = fmaxf(m_run, m_oth);
    float alf = fexp2(m_run - m_tot);
    float l_tot = l_run * alf + l_oth * fexp2(m_oth - m_tot);
    #pragma unroll
    for (int r = 0; r < 16; ++r) { o0[r] *= alf; o1[r] *= alf; }

    float* oArea = (float*)smem + (size_t)p * 2048;   // 8 KB per pair
    if (kh == 1) {
      float* dst = oArea + lane * 32;
      #pragma unroll
      for (int r = 0; r < 16; ++r) { dst[r] = o0[r]; dst[16 + r] = o1[r]; }
    }
    __syncthreads();
    if (kh == 0) {
      const float* src = oArea + lane * 32;
      #pragma unroll
      for (int r = 0; r < 16; ++r) { o0[r] += src[r]; o1[r] += src[16 + r]; }
    }
    __syncthreads();   // o-areas dead; lo regions may overwrite them

    // ---- epilogue (kh==0 waves): normalize, LDS transpose, store ----
    if (kh == 0) {
      unsigned short* lo = (unsigned short*)smem + (size_t)p * 2304;
      float inv = 1.0f / l_tot;
      #pragma unroll
      for (int gg = 0; gg < 8; ++gg) {
        int r = 2 * gg;
        int dl = (r & 3) + 8 * (r >> 2) + 4 * hi;
        unsigned int w0 = (unsigned int)f2bf(o0[r] * inv) | ((unsigned int)f2bf(o0[r + 1] * inv) << 16);
        unsigned int w1 = (unsigned int)f2bf(o1[r] * inv) | ((unsigned int)f2bf(o1[r + 1] * inv) << 16);
        *(unsigned int*)&lo[q * 72 + dl] = w0;
        *(unsigned int*)&lo[q * 72 + 32 + dl] = w1;
      }
      {
        int row = lane >> 1;
        int ch = (lane & 1) * 32;
        uint4 x0 = *(const uint4*)&lo[row * 72 + ch + 0];
        uint4 x1 = *(const uint4*)&lo[row * 72 + ch + 8];
        uint4 x2 = *(const uint4*)&lo[row * 72 + ch + 16];
        uint4 x3 = *(const uint4*)&lo[row * 72 + ch + 24];
        unsigned short* dst = &Ob[(size_t)(b * SEQ + wq0 + row) * (NHEADS * HDIM) + h * HDIM + ch];
        *(uint4*)(dst + 0)  = x0;
        *(uint4*)(dst + 8)  = x1;
        *(uint4*)(dst + 16) = x2;
        *(uint4*)(dst + 24) = x3;
      }
    }
  }
}

// =====================================================================
// launcher
// =====================================================================
extern "C" void kernel_launch(void* const* d_in, const int* in_sizes, int n_in,
                              void* d_out, int out_size, void* d_ws, size_t ws_size,
                              hipStream_t stream) {
  const float* X  = (const float*)d_in[0];
  const float* Wq = (const float*)d_in[1];
  const float* Wk = (const float*)d_in[2];
  const float* Wv = (const float*)d_in[3];
  const float* Wo = (const float*)d_in[4];
  float* out = (float*)d_out;

  char* ws = (char*)d_ws;
  size_t off = 0;
  auto carve = [&](size_t bytes) -> void* {
    void* p = ws + off;
    off += (bytes + 255) & ~(size_t)255;
    return p;
  };
  float* rope_cos = (float*)carve((size_t)SEQ * 32 * 4);
  float* rope_sin = (float*)carve((size_t)SEQ * 32 * 4);
  unsigned short* Xb     = (unsigned short*)carve((size_t)NTOK * HIDDEN * 2);   // reused as Ob
  unsigned short* Wqkv_t = (unsigned short*)carve((size_t)QKVN * HIDDEN * 2);
  unsigned short* Wot    = (unsigned short*)carve((size_t)HIDDEN * HIDDEN * 2);
  unsigned short* QKVb   = (unsigned short*)carve((size_t)NTOK * QKVN * 2);
  unsigned short* Vt     = (unsigned short*)carve((size_t)BATCH * NKV * HDIM * SEQ * 2);
  unsigned short* Ob     = Xb;   // Xb dead after QKV GEMM

  rope_table_kernel<<<dim3(256), dim3(256), 0, stream>>>(rope_cos, rope_sin);
  convert_x_kernel<<<dim3((NTOK * HIDDEN) / (256 * 8)), dim3(256), 0, stream>>>(X, Xb);

  transpose_w_kernel<<<dim3(2048 / 64, HIDDEN / 64), dim3(256), 0, stream>>>(Wq, Wqkv_t, 2048, 0);
  transpose_w_kernel<<<dim3(512 / 64,  HIDDEN / 64), dim3(256), 0, stream>>>(Wk, Wqkv_t, 512, 2048);
  transpose_w_kernel<<<dim3(512 / 64,  HIDDEN / 64), dim3(256), 0, stream>>>(Wv, Wqkv_t, 512, 2560);
  transpose_w_kernel<<<dim3(2048 / 64, HIDDEN / 64), dim3(256), 0, stream>>>(Wo, Wot, 2048, 0);

  // QKV GEMM with fused RoPE (+ Q pre-scale) in the epilogue
  gemm128_kernel<1><<<dim3(QKVN / 128, NTOK / 128), dim3(256), 0, stream>>>(
      Xb, Wqkv_t, QKVb, NTOK, QKVN, HIDDEN, rope_cos, rope_sin);

  v_pack_kernel<<<dim3((NTOK * NKV * HDIM) / 256), dim3(256), 0, stream>>>(QKVb, Vt);

  flash_kernel<<<dim3(8, NHEADS, BATCH), dim3(512), 0, stream>>>(QKVb, Vt, Ob);

  gemm128_kernel<0><<<dim3(HIDDEN / 128, NTOK / 128), dim3(256), 0, stream>>>(
      Ob, Wot, out, NTOK, HIDDEN, HIDDEN, nullptr, nullptr);
}

// Round 15
// 220.788 us; speedup vs baseline: 1.1507x; 1.0070x over previous
//
#include <hip/hip_runtime.h>
#include <cstdint>
#include <cstddef>

// ---------- types ----------
typedef __attribute__((ext_vector_type(8))) short short8;   // 8 bf16 MFMA A/B frag
typedef __attribute__((ext_vector_type(4))) float f32x4;    // 16x16 C/D frag
typedef __attribute__((ext_vector_type(16))) float f32x16;  // 32x32 C/D frag

#define MFMA16(a, b, c) __builtin_amdgcn_mfma_f32_16x16x32_bf16((a), (b), (c), 0, 0, 0)
#define MFMA32(a, b, c) __builtin_amdgcn_mfma_f32_32x32x16_bf16((a), (b), (c), 0, 0, 0)

union F2U { float f; unsigned int u; };
union U4S8 { uint4 u4; unsigned short s[8]; short8 v; };

__device__ __forceinline__ unsigned short f2bf(float f) {
  F2U x; x.f = f;
  unsigned int r = x.u + 0x7fffu + ((x.u >> 16) & 1u);  // RNE
  return (unsigned short)(r >> 16);
}
__device__ __forceinline__ float bf2f(unsigned short s) {
  F2U x; x.u = ((unsigned int)s) << 16;
  return x.f;
}
__device__ __forceinline__ float fexp2(float x) {        // v_exp_f32: D = 2^S0
  float r; asm("v_exp_f32 %0, %1" : "=v"(r) : "v"(x)); return r;
}
__device__ __forceinline__ unsigned int cvtpk(float lo, float hiv) {  // T12
  unsigned int r; asm("v_cvt_pk_bf16_f32 %0, %1, %2" : "=v"(r) : "v"(lo), "v"(hiv)); return r;
}

// ---------- problem constants ----------
#define HIDDEN 2048
#define NHEADS 32
#define NKV 8
#define HDIM 64
#define SEQ 2048
#define BATCH 2
#define NTOK (BATCH * SEQ)   // 4096
#define QKVN 3072            // fused QKV output width (2048 Q | 512 K | 512 V)
#define QSCALE 0.18033688011117309f   // 0.125 * log2(e)

// =====================================================================
// RoPE table: cos/sin [SEQ][32] fp32
// =====================================================================
__global__ __launch_bounds__(256) void rope_table_kernel(float* __restrict__ ct, float* __restrict__ st) {
  int idx = blockIdx.x * 256 + threadIdx.x;     // 0 .. 65535
  int s = idx >> 5;
  int i = idx & 31;
  float invf = expf(-(float)i * (9.210340371976184f / 32.0f));  // 10000^(-i/32)
  float f = (float)s * invf;
  ct[idx] = cosf(f);
  st[idx] = sinf(f);
}

// =====================================================================
// X fp32 -> bf16 (elementwise, vectorized)
// =====================================================================
__global__ __launch_bounds__(256) void convert_x_kernel(const float* __restrict__ X,
                                                        unsigned short* __restrict__ Xb) {
  size_t i = ((size_t)blockIdx.x * 256 + threadIdx.x) * 8;
  float4 a0 = *(const float4*)(X + i);
  float4 a1 = *(const float4*)(X + i + 4);
  U4S8 p;
  p.s[0] = f2bf(a0.x); p.s[1] = f2bf(a0.y); p.s[2] = f2bf(a0.z); p.s[3] = f2bf(a0.w);
  p.s[4] = f2bf(a1.x); p.s[5] = f2bf(a1.y); p.s[6] = f2bf(a1.z); p.s[7] = f2bf(a1.w);
  *(short8*)(Xb + i) = p.v;
}

// =====================================================================
// Weight transpose+convert: W [K=2048][N] fp32 -> Wt[row_off + n][k] bf16
// =====================================================================
__global__ __launch_bounds__(256) void transpose_w_kernel(const float* __restrict__ W,
                                                          unsigned short* __restrict__ Wt,
                                                          int N, int row_off) {
  __shared__ unsigned short lt[64][72];  // [n][k], padded
  const int t = threadIdx.x;
  const int k0 = blockIdx.y * 64, n0 = blockIdx.x * 64;
  #pragma unroll
  for (int p = 0; p < 4; ++p) {
    int kr = p * 16 + (t >> 4);
    int nc = (t & 15) * 4;
    float4 v = *(const float4*)&W[(size_t)(k0 + kr) * N + n0 + nc];
    lt[nc + 0][kr] = f2bf(v.x);
    lt[nc + 1][kr] = f2bf(v.y);
    lt[nc + 2][kr] = f2bf(v.z);
    lt[nc + 3][kr] = f2bf(v.w);
  }
  __syncthreads();
  #pragma unroll
  for (int p = 0; p < 2; ++p) {
    int nr = p * 32 + (t >> 3);
    int kc = (t & 7) * 8;
    *(short8*)&Wt[(size_t)(row_off + n0 + nr) * HIDDEN + k0 + kc] = *(const short8*)&lt[nr][kc];
  }
}

// =====================================================================
// GEMM: C[M,N] = A[M,K] @ Bt[N,K]^T, all bf16 operands.
// 128x128 tile, BK=64, 4 waves; global_load_lds w16 + XOR chunk swizzle;
// T1 XCD-aware block swizzle. Inner loop uses mfma_f32_32x32x16_bf16
// (2382 TF ceiling vs 2075 for 16x16; half the MFMA issue slots, same
// ds_read count/pattern). Per wave: 2x2 frags of 32x32 (64 acc VGPRs).
// A-frag: lane holds A[row=lane&31][k=(lane>>5)*8..+8] (16B read);
// B-frag: lane holds Bt[col=lane&31][k contiguous]; C/D: col=lane&31,
// row=(r&3)+8*(r>>2)+4*(lane>>5)  [HW-verified layouts].
// MODE 0: fp32 out. MODE 1: bf16 out + FUSED ROPE (partner col^32 =
// acc[i][j^1][r], const idx; fi = lane&31 for both j).
// =====================================================================
template<int MODE>
__global__ __launch_bounds__(256) void gemm128_kernel(const unsigned short* __restrict__ Ab,
                                                      const unsigned short* __restrict__ Bt,
                                                      void* __restrict__ Cp,
                                                      int M, int N, int K,
                                                      const float* __restrict__ ct,
                                                      const float* __restrict__ st) {
  __shared__ __align__(16) unsigned short lds_a[128][64];
  __shared__ __align__(16) unsigned short lds_b[128][64];

  const int t = threadIdx.x, lane = t & 63, w = t >> 6;
  const int q32 = lane & 31, hi = lane >> 5;

  // T1: XCD-aware swizzle — contiguous tile chunk per XCD
  const int orig = blockIdx.y * gridDim.x + blockIdx.x;
  const int nwg  = (int)(gridDim.x * gridDim.y);
  const int cpx  = nwg >> 3;                      // nwg % 8 == 0
  const int swz  = (orig & 7) * cpx + (orig >> 3);
  const int m0 = (swz / (int)gridDim.x) * 128;
  const int n0 = (swz % (int)gridDim.x) * 128;

  const int wr = (w >> 1) * 64, wc = (w & 1) * 64;

  f32x16 acc[2][2] = {};   // [m-half][n-half], each 32x32

  for (int k0 = 0; k0 < K; k0 += 64) {
    __syncthreads();
    #pragma unroll
    for (int c = 0; c < 4; ++c) {
      int row = w * 32 + c * 8 + (lane >> 3);
      int cks = (lane & 7) ^ (row & 7);
      __builtin_amdgcn_global_load_lds(
          (const __attribute__((address_space(1))) unsigned int*)(Ab + (size_t)(m0 + row) * K + k0 + cks * 8),
          (__attribute__((address_space(3))) unsigned int*)&lds_a[w * 32 + c * 8][0], 16, 0, 0);
      __builtin_amdgcn_global_load_lds(
          (const __attribute__((address_space(1))) unsigned int*)(Bt + (size_t)(n0 + row) * K + k0 + cks * 8),
          (__attribute__((address_space(3))) unsigned int*)&lds_b[w * 32 + c * 8][0], 16, 0, 0);
    }
    __syncthreads();

    #pragma unroll
    for (int kq = 0; kq < 4; ++kq) {           // K=16 per MFMA32, BK=64
      short8 af[2], bf[2];
      #pragma unroll
      for (int i = 0; i < 2; ++i) {
        int row = wr + i * 32 + q32;
        af[i] = *(const short8*)((const char*)&lds_a[0][0] + row * 128 + (((kq * 2 + hi) ^ (row & 7)) * 16));
      }
      #pragma unroll
      for (int j = 0; j < 2; ++j) {
        int row = wc + j * 32 + q32;
        bf[j] = *(const short8*)((const char*)&lds_b[0][0] + row * 128 + (((kq * 2 + hi) ^ (row & 7)) * 16));
      }
      acc[0][0] = MFMA32(af[0], bf[0], acc[0][0]);
      acc[0][1] = MFMA32(af[0], bf[1], acc[0][1]);
      acc[1][0] = MFMA32(af[1], bf[0], acc[1][0]);
      acc[1][1] = MFMA32(af[1], bf[1], acc[1][1]);
    }
  }

  if constexpr (MODE == 0) {
    #pragma unroll
    for (int i = 0; i < 2; ++i)
      #pragma unroll
      for (int j = 0; j < 2; ++j)
        #pragma unroll
        for (int r = 0; r < 16; ++r) {
          int row = m0 + wr + i * 32 + (r & 3) + 8 * (r >> 2) + 4 * hi;
          int col = n0 + wc + j * 32 + q32;
          ((float*)Cp)[(size_t)row * N + col] = acc[i][j][r];
        }
  } else {
    const bool isV = (n0 >= 2560);
    const bool isQ = (n0 < 2048);
    #pragma unroll
    for (int i = 0; i < 2; ++i)
      #pragma unroll
      for (int r = 0; r < 16; ++r) {
        int row = m0 + wr + i * 32 + (r & 3) + 8 * (r >> 2) + 4 * hi;
        int s_tok = row & (SEQ - 1);
        float cc = 0.f, ss = 0.f;
        if (!isV) {
          cc = ct[s_tok * 32 + q32];   // fi = lane&31 for BOTH n-halves
          ss = st[s_tok * 32 + q32];
        }
        #pragma unroll
        for (int j = 0; j < 2; ++j) {
          int col = n0 + wc + j * 32 + q32;
          float v = acc[i][j][r];
          float o;
          if (isV) {
            o = v;
          } else {
            float pp = acc[i][j ^ 1][r];        // partner col^32 (const idx)
            o = (j == 0) ? (v * cc - pp * ss) : (v * cc + pp * ss);  // rotate_half
            if (isQ) o *= QSCALE;
          }
          ((unsigned short*)Cp)[(size_t)row * N + col] = f2bf(o);
        }
      }
  }
}

// =====================================================================
// V pack/transpose: QKVb cols 2560.. -> Vt [B][KV][64][S] bf16
// =====================================================================
__global__ __launch_bounds__(256) void v_pack_kernel(const unsigned short* __restrict__ QKV,
                                                     unsigned short* __restrict__ Vt) {
  int idx = blockIdx.x * 256 + threadIdx.x;
  int m = idx >> 9;
  int c = idx & 511;
  int b = m >> 11, s = m & 2047;
  int kv = c >> 6, d = c & 63;
  Vt[(((size_t)(b * NKV + kv)) * HDIM + d) * SEQ + s] = QKV[(size_t)m * QKVN + 2560 + c];
}

// =====================================================================
// Flash attention, SPLIT-K wave pairs + balanced-pair grid (R14, frozen).
// =====================================================================
#define KVBLK 64

__global__ __launch_bounds__(512, 4) void flash_kernel(const unsigned short* __restrict__ QKV,
                                                       const unsigned short* __restrict__ Vt,
                                                       unsigned short* __restrict__ Ob) {
  const int bx = blockIdx.x;     // 0..7 (pair index)
  const int h = blockIdx.y;
  const int b = blockIdx.z;
  const int kv = h >> 2;
  const int t = threadIdx.x;
  const int lane = t & 63;
  const int w = t >> 6;          // 0..7
  const int p = w >> 1;          // q-row group 0..3
  const int kh = w & 1;          // key half 0/1
  const int q = lane & 31;
  const int hi = lane >> 5;

  __shared__ __align__(16) char smem[34816];
  unsigned short* Klds = (unsigned short*)smem;
  unsigned short* Vlds = (unsigned short*)(smem + 16384);
  float* mlArea = (float*)(smem + 32768);   // [wave][q][{m,l}]

  const unsigned short* Kg = QKV + (size_t)b * SEQ * QKVN + 2048 + kv * 64;
  const unsigned short* Vg = Vt + ((size_t)(b * NKV + kv)) * HDIM * SEQ;
  const unsigned short* Qh = QKV + (size_t)b * SEQ * QKVN + h * 64;

  const int srow = w * 8 + (lane >> 3);
  const int scks = (lane & 7) ^ (srow & 7);
  const unsigned short* Ksrc = Kg + (size_t)srow * QKVN + scks * 8;   // + kt0*QKVN
  const unsigned short* Vsrc = Vg + (size_t)srow * SEQ + scks * 8;    // + kt0

  #define STAGE_KV(buf, kt0)                                                              \
    do {                                                                                  \
      __builtin_amdgcn_global_load_lds(                                                   \
          (const __attribute__((address_space(1))) unsigned int*)(Ksrc + (size_t)(kt0) * QKVN), \
          (__attribute__((address_space(3))) unsigned int*)(Klds + (buf) * 4096 + w * 512), 16, 0, 0); \
      __builtin_amdgcn_global_load_lds(                                                   \
          (const __attribute__((address_space(1))) unsigned int*)(Vsrc + (kt0)),          \
          (__attribute__((address_space(3))) unsigned int*)(Vlds + (buf) * 4096 + w * 512), 16, 0, 0); \
    } while (0)

  #pragma unroll 1
  for (int seg = 0; seg < 2; ++seg) {
    const int qb = seg ? bx : (15 - bx);
    const int wq0 = qb * 128 + p * 32;

    short8 qf[4];
    #pragma unroll
    for (int f = 0; f < 4; ++f)
      qf[f] = *(const short8*)&Qh[(size_t)(wq0 + q) * QKVN + f * 16 + hi * 8];

    f32x16 o0 = {}, o1 = {};
    float m_run = -1e30f, l_run = 0.f;

    const int nt_blk = qb * 2 + 2;

    __syncthreads();
    STAGE_KV(0, 0);
    __syncthreads();
    int cur = 0;

    for (int tt = 0; tt < nt_blk; ++tt) {
      if (tt + 1 < nt_blk) STAGE_KV(cur ^ 1, (tt + 1) * KVBLK);

      const int kbase = tt * KVBLK + kh * 32;
      if (kbase <= wq0 + 31) {
        const unsigned short* Kt = Klds + cur * 4096;
        const unsigned short* Vl = Vlds + cur * 4096;

        f32x16 s = {};
        __builtin_amdgcn_s_setprio(1);
        #pragma unroll
        for (int f = 0; f < 4; ++f) {
          short8 kf = *(const short8*)(Kt + (kh * 32 + q) * 64 + (((f * 2 + hi) ^ (q & 7)) * 8));
          s = MFMA32(kf, qf[f], s);
        }
        __builtin_amdgcn_s_setprio(0);

        if (kbase + 31 > wq0) {
          #pragma unroll
          for (int r = 0; r < 16; ++r) {
            int kl = (r & 3) + 8 * (r >> 2) + 4 * hi;
            if (kbase + kl > wq0 + q) s[r] = -1e30f;
          }
        }

        float mt = -1e30f;
        #pragma unroll
        for (int r = 0; r < 16; ++r) mt = fmaxf(mt, s[r]);
        mt = fmaxf(mt, __shfl_xor(mt, 32, 64));

        const bool resc = __any(mt > m_run + 11.0f);
        if (resc) {
          float mn = fmaxf(m_run, mt);
          float alpha = fexp2(m_run - mn);
          m_run = mn;
          l_run *= alpha;
          #pragma unroll
          for (int r = 0; r < 16; ++r) { o0[r] *= alpha; o1[r] *= alpha; }
        }
        float ls = 0.f;
        #pragma unroll
        for (int r = 0; r < 16; ++r) {
          float pp = fexp2(s[r] - m_run);
          s[r] = pp;
          ls += pp;
        }
        ls += __shfl_xor(ls, 32, 64);
        l_run += ls;

        unsigned int own[8], rcv[8];
        #pragma unroll
        for (int g = 0; g < 8; ++g)
          own[g] = cvtpk(s[2 * g], s[2 * g + 1]);
        #pragma unroll
        for (int g = 0; g < 8; ++g)
          rcv[g] = (unsigned int)__shfl_xor((int)own[g], 32, 64);

        __builtin_amdgcn_s_setprio(1);
        {
          U4S8 pfv;
          pfv.u4.x = hi ? rcv[2] : own[0];
          pfv.u4.y = hi ? rcv[3] : own[1];
          pfv.u4.z = hi ? own[2] : rcv[0];
          pfv.u4.w = hi ? own[3] : rcv[1];
          int co = ((kh * 4 + hi) ^ (q & 7)) * 8;
          short8 vf0 = *(const short8*)(Vl + q * 64 + co);
          short8 vf1 = *(const short8*)(Vl + (32 + q) * 64 + co);
          o0 = MFMA32(vf0, pfv.v, o0);
          o1 = MFMA32(vf1, pfv.v, o1);
        }
        {
          U4S8 pfv;
          pfv.u4.x = hi ? rcv[6] : own[4];
          pfv.u4.y = hi ? rcv[7] : own[5];
          pfv.u4.z = hi ? own[6] : rcv[4];
          pfv.u4.w = hi ? own[7] : rcv[5];
          int co = ((kh * 4 + 2 + hi) ^ (q & 7)) * 8;
          short8 vf0 = *(const short8*)(Vl + q * 64 + co);
          short8 vf1 = *(const short8*)(Vl + (32 + q) * 64 + co);
          o0 = MFMA32(vf0, pfv.v, o0);
          o1 = MFMA32(vf1, pfv.v, o1);
        }
        __builtin_amdgcn_s_setprio(0);
      }

      __syncthreads();
      cur ^= 1;
    }

    // ============ cross-wave (split-K) merge, per pair ============
    if (hi == 0) {
      mlArea[(w * 32 + q) * 2 + 0] = m_run;
      mlArea[(w * 32 + q) * 2 + 1] = l_run;
    }
    __syncthreads();
    const int wo = p * 2 + (kh ^ 1);
    float m_oth = mlArea[(wo * 32 + q) * 2 + 0];
    float l_oth = mlArea[(wo * 32 + q) * 2 + 1];
    float m_tot = fmaxf(m_run, m_oth);
    float alf = fexp2(m_run - m_tot);
    float l_tot = l_run * alf + l_oth * fexp2(m_oth - m_tot);
    #pragma unroll
    for (int r = 0; r < 16; ++r) { o0[r] *= alf; o1[r] *= alf; }

    float* oArea = (float*)smem + (size_t)p * 2048;
    if (kh == 1) {
      float* dst = oArea + lane * 32;
      #pragma unroll
      for (int r = 0; r < 16; ++r) { dst[r] = o0[r]; dst[16 + r] = o1[r]; }
    }
    __syncthreads();
    if (kh == 0) {
      const float* src = oArea + lane * 32;
      #pragma unroll
      for (int r = 0; r < 16; ++r) { o0[r] += src[r]; o1[r] += src[16 + r]; }
    }
    __syncthreads();

    if (kh == 0) {
      unsigned short* lo = (unsigned short*)smem + (size_t)p * 2304;
      float inv = 1.0f / l_tot;
      #pragma unroll
      for (int gg = 0; gg < 8; ++gg) {
        int r = 2 * gg;
        int dl = (r & 3) + 8 * (r >> 2) + 4 * hi;
        unsigned int w0 = (unsigned int)f2bf(o0[r] * inv) | ((unsigned int)f2bf(o0[r + 1] * inv) << 16);
        unsigned int w1 = (unsigned int)f2bf(o1[r] * inv) | ((unsigned int)f2bf(o1[r + 1] * inv) << 16);
        *(unsigned int*)&lo[q * 72 + dl] = w0;
        *(unsigned int*)&lo[q * 72 + 32 + dl] = w1;
      }
      {
        int row = lane >> 1;
        int ch = (lane & 1) * 32;
        uint4 x0 = *(const uint4*)&lo[row * 72 + ch + 0];
        uint4 x1 = *(const uint4*)&lo[row * 72 + ch + 8];
        uint4 x2 = *(const uint4*)&lo[row * 72 + ch + 16];
        uint4 x3 = *(const uint4*)&lo[row * 72 + ch + 24];
        unsigned short* dst = &Ob[(size_t)(b * SEQ + wq0 + row) * (NHEADS * HDIM) + h * HDIM + ch];
        *(uint4*)(dst + 0)  = x0;
        *(uint4*)(dst + 8)  = x1;
        *(uint4*)(dst + 16) = x2;
        *(uint4*)(dst + 24) = x3;
      }
    }
  }
}

// =====================================================================
// launcher
// =====================================================================
extern "C" void kernel_launch(void* const* d_in, const int* in_sizes, int n_in,
                              void* d_out, int out_size, void* d_ws, size_t ws_size,
                              hipStream_t stream) {
  const float* X  = (const float*)d_in[0];
  const float* Wq = (const float*)d_in[1];
  const float* Wk = (const float*)d_in[2];
  const float* Wv = (const float*)d_in[3];
  const float* Wo = (const float*)d_in[4];
  float* out = (float*)d_out;

  char* ws = (char*)d_ws;
  size_t off = 0;
  auto carve = [&](size_t bytes) -> void* {
    void* p = ws + off;
    off += (bytes + 255) & ~(size_t)255;
    return p;
  };
  float* rope_cos = (float*)carve((size_t)SEQ * 32 * 4);
  float* rope_sin = (float*)carve((size_t)SEQ * 32 * 4);
  unsigned short* Xb     = (unsigned short*)carve((size_t)NTOK * HIDDEN * 2);   // reused as Ob
  unsigned short* Wqkv_t = (unsigned short*)carve((size_t)QKVN * HIDDEN * 2);
  unsigned short* Wot    = (unsigned short*)carve((size_t)HIDDEN * HIDDEN * 2);
  unsigned short* QKVb   = (unsigned short*)carve((size_t)NTOK * QKVN * 2);
  unsigned short* Vt     = (unsigned short*)carve((size_t)BATCH * NKV * HDIM * SEQ * 2);
  unsigned short* Ob     = Xb;   // Xb dead after QKV GEMM

  rope_table_kernel<<<dim3(256), dim3(256), 0, stream>>>(rope_cos, rope_sin);
  convert_x_kernel<<<dim3((NTOK * HIDDEN) / (256 * 8)), dim3(256), 0, stream>>>(X, Xb);

  transpose_w_kernel<<<dim3(2048 / 64, HIDDEN / 64), dim3(256), 0, stream>>>(Wq, Wqkv_t, 2048, 0);
  transpose_w_kernel<<<dim3(512 / 64,  HIDDEN / 64), dim3(256), 0, stream>>>(Wk, Wqkv_t, 512, 2048);
  transpose_w_kernel<<<dim3(512 / 64,  HIDDEN / 64), dim3(256), 0, stream>>>(Wv, Wqkv_t, 512, 2560);
  transpose_w_kernel<<<dim3(2048 / 64, HIDDEN / 64), dim3(256), 0, stream>>>(Wo, Wot, 2048, 0);

  // QKV GEMM with fused RoPE (+ Q pre-scale) in the epilogue
  gemm128_kernel<1><<<dim3(QKVN / 128, NTOK / 128), dim3(256), 0, stream>>>(
      Xb, Wqkv_t, QKVb, NTOK, QKVN, HIDDEN, rope_cos, rope_sin);

  v_pack_kernel<<<dim3((NTOK * NKV * HDIM) / 256), dim3(256), 0, stream>>>(QKVb, Vt);

  flash_kernel<<<dim3(8, NHEADS, BATCH), dim3(512), 0, stream>>>(QKVb, Vt, Ob);

  gemm128_kernel<0><<<dim3(HIDDEN / 128, NTOK / 128), dim3(256), 0, stream>>>(
      Ob, Wot, out, NTOK, HIDDEN, HIDDEN, nullptr, nullptr);
}

// Round 16
// 203.502 us; speedup vs baseline: 1.2484x; 1.0849x over previous
//
#include <hip/hip_runtime.h>
#include <cstdint>
#include <cstddef>

// ---------- types ----------
typedef __attribute__((ext_vector_type(8))) short short8;   // 8 bf16 MFMA A/B frag
typedef __attribute__((ext_vector_type(4))) float f32x4;    // 16x16 C/D frag
typedef __attribute__((ext_vector_type(16))) float f32x16;  // 32x32 C/D frag

#define MFMA16(a, b, c) __builtin_amdgcn_mfma_f32_16x16x32_bf16((a), (b), (c), 0, 0, 0)
#define MFMA32(a, b, c) __builtin_amdgcn_mfma_f32_32x32x16_bf16((a), (b), (c), 0, 0, 0)

union F2U { float f; unsigned int u; };
union U4S8 { uint4 u4; unsigned short s[8]; short8 v; };

__device__ __forceinline__ unsigned short f2bf(float f) {
  F2U x; x.f = f;
  unsigned int r = x.u + 0x7fffu + ((x.u >> 16) & 1u);  // RNE
  return (unsigned short)(r >> 16);
}
__device__ __forceinline__ float bf2f(unsigned short s) {
  F2U x; x.u = ((unsigned int)s) << 16;
  return x.f;
}
__device__ __forceinline__ float fexp2(float x) {        // v_exp_f32: D = 2^S0
  float r; asm("v_exp_f32 %0, %1" : "=v"(r) : "v"(x)); return r;
}
__device__ __forceinline__ unsigned int cvtpk(float lo, float hiv) {  // T12
  unsigned int r; asm("v_cvt_pk_bf16_f32 %0, %1, %2" : "=v"(r) : "v"(lo), "v"(hiv)); return r;
}

// ---------- problem constants ----------
#define HIDDEN 2048
#define NHEADS 32
#define NKV 8
#define HDIM 64
#define SEQ 2048
#define BATCH 2
#define NTOK (BATCH * SEQ)   // 4096
#define QKVN 3072            // fused QKV output width (2048 Q | 512 K | 512 V)
#define QSCALE 0.18033688011117309f   // 0.125 * log2(e)

// =====================================================================
// Fused prep kernel (one launch):
//   blocks [0,256):        RoPE cos/sin tables [SEQ][32] fp32
//   blocks [256,4352):     X fp32 -> bf16 (4096 blocks)
//   blocks [4352,6912):    weight transpose+convert (Wq|Wk|Wv|Wo, 2560)
// =====================================================================
__global__ __launch_bounds__(256) void prep_kernel(const float* __restrict__ X,
                                                   const float* __restrict__ Wq,
                                                   const float* __restrict__ Wk,
                                                   const float* __restrict__ Wv,
                                                   const float* __restrict__ Wo,
                                                   unsigned short* __restrict__ Xb,
                                                   unsigned short* __restrict__ Wqkv_t,
                                                   unsigned short* __restrict__ Wot,
                                                   float* __restrict__ ct,
                                                   float* __restrict__ st) {
  __shared__ unsigned short lt[64][72];
  int bid = blockIdx.x;
  const int t = threadIdx.x;

  if (bid < 256) {                       // ---- rope tables ----
    int idx = bid * 256 + t;             // 0 .. 65535
    int s = idx >> 5;
    int i = idx & 31;
    float invf = expf(-(float)i * (9.210340371976184f / 32.0f));  // 10000^(-i/32)
    float f = (float)s * invf;
    ct[idx] = cosf(f);
    st[idx] = sinf(f);
    return;
  }
  bid -= 256;
  if (bid < 4096) {                      // ---- X convert ----
    size_t i = ((size_t)bid * 256 + t) * 8;
    float4 a0 = *(const float4*)(X + i);
    float4 a1 = *(const float4*)(X + i + 4);
    U4S8 p;
    p.s[0] = f2bf(a0.x); p.s[1] = f2bf(a0.y); p.s[2] = f2bf(a0.z); p.s[3] = f2bf(a0.w);
    p.s[4] = f2bf(a1.x); p.s[5] = f2bf(a1.y); p.s[6] = f2bf(a1.z); p.s[7] = f2bf(a1.w);
    *(short8*)(Xb + i) = p.v;
    return;
  }
  bid -= 4096;
  // ---- weight transposes ----
  const float* W; unsigned short* Wt; int N, row_off, bx, by;
  if (bid < 1024)      { W = Wq; Wt = Wqkv_t; N = 2048; row_off = 0;    bx = bid & 31; by = bid >> 5; }
  else if (bid < 1280) { bid -= 1024; W = Wk; Wt = Wqkv_t; N = 512; row_off = 2048; bx = bid & 7; by = bid >> 3; }
  else if (bid < 1536) { bid -= 1280; W = Wv; Wt = Wqkv_t; N = 512; row_off = 2560; bx = bid & 7; by = bid >> 3; }
  else                 { bid -= 1536; W = Wo; Wt = Wot;    N = 2048; row_off = 0;   bx = bid & 31; by = bid >> 5; }
  const int k0 = by * 64, n0 = bx * 64;
  #pragma unroll
  for (int p = 0; p < 4; ++p) {
    int kr = p * 16 + (t >> 4);
    int nc = (t & 15) * 4;
    float4 v = *(const float4*)&W[(size_t)(k0 + kr) * N + n0 + nc];
    lt[nc + 0][kr] = f2bf(v.x);
    lt[nc + 1][kr] = f2bf(v.y);
    lt[nc + 2][kr] = f2bf(v.z);
    lt[nc + 3][kr] = f2bf(v.w);
  }
  __syncthreads();
  #pragma unroll
  for (int p = 0; p < 2; ++p) {
    int nr = p * 32 + (t >> 3);
    int kc = (t & 7) * 8;
    *(short8*)&Wt[(size_t)(row_off + n0 + nr) * HIDDEN + k0 + kc] = *(const short8*)&lt[nr][kc];
  }
}

// =====================================================================
// GEMM: C[M,N] = A[M,K] @ Bt[N,K]^T, all bf16 operands.
// 128x128 tile, BK=64, 4 waves; global_load_lds w16 + XOR chunk swizzle;
// T1 XCD swizzle; mfma_f32_32x32x16_bf16 inner loop (R15, kept).
// MODE 0: fp32 out. MODE 1: bf16 out + FUSED ROPE.
// =====================================================================
template<int MODE>
__global__ __launch_bounds__(256) void gemm128_kernel(const unsigned short* __restrict__ Ab,
                                                      const unsigned short* __restrict__ Bt,
                                                      void* __restrict__ Cp,
                                                      int M, int N, int K,
                                                      const float* __restrict__ ct,
                                                      const float* __restrict__ st) {
  __shared__ __align__(16) unsigned short lds_a[128][64];
  __shared__ __align__(16) unsigned short lds_b[128][64];

  const int t = threadIdx.x, lane = t & 63, w = t >> 6;
  const int q32 = lane & 31, hi = lane >> 5;

  const int orig = blockIdx.y * gridDim.x + blockIdx.x;
  const int nwg  = (int)(gridDim.x * gridDim.y);
  const int cpx  = nwg >> 3;                      // nwg % 8 == 0
  const int swz  = (orig & 7) * cpx + (orig >> 3);
  const int m0 = (swz / (int)gridDim.x) * 128;
  const int n0 = (swz % (int)gridDim.x) * 128;

  const int wr = (w >> 1) * 64, wc = (w & 1) * 64;

  f32x16 acc[2][2] = {};   // [m-half][n-half], each 32x32

  for (int k0 = 0; k0 < K; k0 += 64) {
    __syncthreads();
    #pragma unroll
    for (int c = 0; c < 4; ++c) {
      int row = w * 32 + c * 8 + (lane >> 3);
      int cks = (lane & 7) ^ (row & 7);
      __builtin_amdgcn_global_load_lds(
          (const __attribute__((address_space(1))) unsigned int*)(Ab + (size_t)(m0 + row) * K + k0 + cks * 8),
          (__attribute__((address_space(3))) unsigned int*)&lds_a[w * 32 + c * 8][0], 16, 0, 0);
      __builtin_amdgcn_global_load_lds(
          (const __attribute__((address_space(1))) unsigned int*)(Bt + (size_t)(n0 + row) * K + k0 + cks * 8),
          (__attribute__((address_space(3))) unsigned int*)&lds_b[w * 32 + c * 8][0], 16, 0, 0);
    }
    __syncthreads();

    #pragma unroll
    for (int kq = 0; kq < 4; ++kq) {           // K=16 per MFMA32, BK=64
      short8 af[2], bf[2];
      #pragma unroll
      for (int i = 0; i < 2; ++i) {
        int row = wr + i * 32 + q32;
        af[i] = *(const short8*)((const char*)&lds_a[0][0] + row * 128 + (((kq * 2 + hi) ^ (row & 7)) * 16));
      }
      #pragma unroll
      for (int j = 0; j < 2; ++j) {
        int row = wc + j * 32 + q32;
        bf[j] = *(const short8*)((const char*)&lds_b[0][0] + row * 128 + (((kq * 2 + hi) ^ (row & 7)) * 16));
      }
      acc[0][0] = MFMA32(af[0], bf[0], acc[0][0]);
      acc[0][1] = MFMA32(af[0], bf[1], acc[0][1]);
      acc[1][0] = MFMA32(af[1], bf[0], acc[1][0]);
      acc[1][1] = MFMA32(af[1], bf[1], acc[1][1]);
    }
  }

  if constexpr (MODE == 0) {
    #pragma unroll
    for (int i = 0; i < 2; ++i)
      #pragma unroll
      for (int j = 0; j < 2; ++j)
        #pragma unroll
        for (int r = 0; r < 16; ++r) {
          int row = m0 + wr + i * 32 + (r & 3) + 8 * (r >> 2) + 4 * hi;
          int col = n0 + wc + j * 32 + q32;
          ((float*)Cp)[(size_t)row * N + col] = acc[i][j][r];
        }
  } else {
    const bool isV = (n0 >= 2560);
    const bool isQ = (n0 < 2048);
    #pragma unroll
    for (int i = 0; i < 2; ++i)
      #pragma unroll
      for (int r = 0; r < 16; ++r) {
        int row = m0 + wr + i * 32 + (r & 3) + 8 * (r >> 2) + 4 * hi;
        int s_tok = row & (SEQ - 1);
        float cc = 0.f, ss = 0.f;
        if (!isV) {
          cc = ct[s_tok * 32 + q32];
          ss = st[s_tok * 32 + q32];
        }
        #pragma unroll
        for (int j = 0; j < 2; ++j) {
          int col = n0 + wc + j * 32 + q32;
          float v = acc[i][j][r];
          float o;
          if (isV) {
            o = v;
          } else {
            float pp = acc[i][j ^ 1][r];        // partner col^32 (const idx)
            o = (j == 0) ? (v * cc - pp * ss) : (v * cc + pp * ss);  // rotate_half
            if (isQ) o *= QSCALE;
          }
          ((unsigned short*)Cp)[(size_t)row * N + col] = f2bf(o);
        }
      }
  }
}

// =====================================================================
// V pack/transpose: QKVb cols 2560.. -> Vt [B][KV][64][S] bf16
// =====================================================================
__global__ __launch_bounds__(256) void v_pack_kernel(const unsigned short* __restrict__ QKV,
                                                     unsigned short* __restrict__ Vt) {
  int idx = blockIdx.x * 256 + threadIdx.x;
  int m = idx >> 9;
  int c = idx & 511;
  int b = m >> 11, s = m & 2047;
  int kv = c >> 6, d = c & 63;
  Vt[(((size_t)(b * NKV + kv)) * HDIM + d) * SEQ + s] = QKV[(size_t)m * QKVN + 2560 + c];
}

// =====================================================================
// Flash attention, SPLIT-K wave pairs + balanced-pair grid (R14) with
// T12 proper: pack-exchange via v_permlane32_swap_b32 — swap(own0,own2)
// yields EXACTLY {hi?rcv2:own0, hi?own2:rcv0}, so 4 swaps per half
// replace 8 shfl_xor + 8 selects. All other structure frozen.
// =====================================================================
#define KVBLK 64

__global__ __launch_bounds__(512, 4) void flash_kernel(const unsigned short* __restrict__ QKV,
                                                       const unsigned short* __restrict__ Vt,
                                                       unsigned short* __restrict__ Ob) {
  const int bx = blockIdx.x;     // 0..7 (pair index)
  const int h = blockIdx.y;
  const int b = blockIdx.z;
  const int kv = h >> 2;
  const int t = threadIdx.x;
  const int lane = t & 63;
  const int w = t >> 6;          // 0..7
  const int p = w >> 1;          // q-row group 0..3
  const int kh = w & 1;          // key half 0/1
  const int q = lane & 31;
  const int hi = lane >> 5;

  __shared__ __align__(16) char smem[34816];
  unsigned short* Klds = (unsigned short*)smem;
  unsigned short* Vlds = (unsigned short*)(smem + 16384);
  float* mlArea = (float*)(smem + 32768);   // [wave][q][{m,l}]

  const unsigned short* Kg = QKV + (size_t)b * SEQ * QKVN + 2048 + kv * 64;
  const unsigned short* Vg = Vt + ((size_t)(b * NKV + kv)) * HDIM * SEQ;
  const unsigned short* Qh = QKV + (size_t)b * SEQ * QKVN + h * 64;

  const int srow = w * 8 + (lane >> 3);
  const int scks = (lane & 7) ^ (srow & 7);
  const unsigned short* Ksrc = Kg + (size_t)srow * QKVN + scks * 8;   // + kt0*QKVN
  const unsigned short* Vsrc = Vg + (size_t)srow * SEQ + scks * 8;    // + kt0

  #define STAGE_KV(buf, kt0)                                                              \
    do {                                                                                  \
      __builtin_amdgcn_global_load_lds(                                                   \
          (const __attribute__((address_space(1))) unsigned int*)(Ksrc + (size_t)(kt0) * QKVN), \
          (__attribute__((address_space(3))) unsigned int*)(Klds + (buf) * 4096 + w * 512), 16, 0, 0); \
      __builtin_amdgcn_global_load_lds(                                                   \
          (const __attribute__((address_space(1))) unsigned int*)(Vsrc + (kt0)),          \
          (__attribute__((address_space(3))) unsigned int*)(Vlds + (buf) * 4096 + w * 512), 16, 0, 0); \
    } while (0)

  #pragma unroll 1
  for (int seg = 0; seg < 2; ++seg) {
    const int qb = seg ? bx : (15 - bx);
    const int wq0 = qb * 128 + p * 32;

    short8 qf[4];
    #pragma unroll
    for (int f = 0; f < 4; ++f)
      qf[f] = *(const short8*)&Qh[(size_t)(wq0 + q) * QKVN + f * 16 + hi * 8];

    f32x16 o0 = {}, o1 = {};
    float m_run = -1e30f, l_run = 0.f;

    const int nt_blk = qb * 2 + 2;

    __syncthreads();
    STAGE_KV(0, 0);
    __syncthreads();
    int cur = 0;

    for (int tt = 0; tt < nt_blk; ++tt) {
      if (tt + 1 < nt_blk) STAGE_KV(cur ^ 1, (tt + 1) * KVBLK);

      const int kbase = tt * KVBLK + kh * 32;
      if (kbase <= wq0 + 31) {
        const unsigned short* Kt = Klds + cur * 4096;
        const unsigned short* Vl = Vlds + cur * 4096;

        f32x16 s = {};
        __builtin_amdgcn_s_setprio(1);
        #pragma unroll
        for (int f = 0; f < 4; ++f) {
          short8 kf = *(const short8*)(Kt + (kh * 32 + q) * 64 + (((f * 2 + hi) ^ (q & 7)) * 8));
          s = MFMA32(kf, qf[f], s);
        }
        __builtin_amdgcn_s_setprio(0);

        if (kbase + 31 > wq0) {
          #pragma unroll
          for (int r = 0; r < 16; ++r) {
            int kl = (r & 3) + 8 * (r >> 2) + 4 * hi;
            if (kbase + kl > wq0 + q) s[r] = -1e30f;
          }
        }

        float mt = -1e30f;
        #pragma unroll
        for (int r = 0; r < 16; ++r) mt = fmaxf(mt, s[r]);
        mt = fmaxf(mt, __shfl_xor(mt, 32, 64));

        const bool resc = __any(mt > m_run + 11.0f);
        if (resc) {
          float mn = fmaxf(m_run, mt);
          float alpha = fexp2(m_run - mn);
          m_run = mn;
          l_run *= alpha;
          #pragma unroll
          for (int r = 0; r < 16; ++r) { o0[r] *= alpha; o1[r] *= alpha; }
        }
        float ls = 0.f;
        #pragma unroll
        for (int r = 0; r < 16; ++r) {
          float pp = fexp2(s[r] - m_run);
          s[r] = pp;
          ls += pp;
        }
        ls += __shfl_xor(ls, 32, 64);
        l_run += ls;

        // ---- pack P -> bf16 pairs (cvt_pk) ----
        unsigned int own[8];
        #pragma unroll
        for (int g = 0; g < 8; ++g)
          own[g] = cvtpk(s[2 * g], s[2 * g + 1]);

        // ---- P^T frags via permlane32_swap + PV ----
        __builtin_amdgcn_s_setprio(1);
        {
          unsigned int pa0 = own[0], pb0 = own[2];
          unsigned int pa1 = own[1], pb1 = own[3];
          asm("v_permlane32_swap_b32 %0, %1" : "+v"(pa0), "+v"(pb0));
          asm("v_permlane32_swap_b32 %0, %1" : "+v"(pa1), "+v"(pb1));
          U4S8 pfv;
          pfv.u4.x = pa0;  // = hi ? rcv[2] : own[0]
          pfv.u4.y = pa1;  // = hi ? rcv[3] : own[1]
          pfv.u4.z = pb0;  // = hi ? own[2] : rcv[0]
          pfv.u4.w = pb1;  // = hi ? own[3] : rcv[1]
          int co = ((kh * 4 + hi) ^ (q & 7)) * 8;
          short8 vf0 = *(const short8*)(Vl + q * 64 + co);
          short8 vf1 = *(const short8*)(Vl + (32 + q) * 64 + co);
          o0 = MFMA32(vf0, pfv.v, o0);
          o1 = MFMA32(vf1, pfv.v, o1);
        }
        {
          unsigned int pa0 = own[4], pb0 = own[6];
          unsigned int pa1 = own[5], pb1 = own[7];
          asm("v_permlane32_swap_b32 %0, %1" : "+v"(pa0), "+v"(pb0));
          asm("v_permlane32_swap_b32 %0, %1" : "+v"(pa1), "+v"(pb1));
          U4S8 pfv;
          pfv.u4.x = pa0;  // = hi ? rcv[6] : own[4]
          pfv.u4.y = pa1;  // = hi ? rcv[7] : own[5]
          pfv.u4.z = pb0;  // = hi ? own[6] : rcv[4]
          pfv.u4.w = pb1;  // = hi ? own[7] : rcv[5]
          int co = ((kh * 4 + 2 + hi) ^ (q & 7)) * 8;
          short8 vf0 = *(const short8*)(Vl + q * 64 + co);
          short8 vf1 = *(const short8*)(Vl + (32 + q) * 64 + co);
          o0 = MFMA32(vf0, pfv.v, o0);
          o1 = MFMA32(vf1, pfv.v, o1);
        }
        __builtin_amdgcn_s_setprio(0);
      }

      __syncthreads();
      cur ^= 1;
    }

    // ============ cross-wave (split-K) merge, per pair ============
    if (hi == 0) {
      mlArea[(w * 32 + q) * 2 + 0] = m_run;
      mlArea[(w * 32 + q) * 2 + 1] = l_run;
    }
    __syncthreads();
    const int wo = p * 2 + (kh ^ 1);
    float m_oth = mlArea[(wo * 32 + q) * 2 + 0];
    float l_oth = mlArea[(wo * 32 + q) * 2 + 1];
    float m_tot = fmaxf(m_run, m_oth);
    float alf = fexp2(m_run - m_tot);
    float l_tot = l_run * alf + l_oth * fexp2(m_oth - m_tot);
    #pragma unroll
    for (int r = 0; r < 16; ++r) { o0[r] *= alf; o1[r] *= alf; }

    float* oArea = (float*)smem + (size_t)p * 2048;
    if (kh == 1) {
      float* dst = oArea + lane * 32;
      #pragma unroll
      for (int r = 0; r < 16; ++r) { dst[r] = o0[r]; dst[16 + r] = o1[r]; }
    }
    __syncthreads();
    if (kh == 0) {
      const float* src = oArea + lane * 32;
      #pragma unroll
      for (int r = 0; r < 16; ++r) { o0[r] += src[r]; o1[r] += src[16 + r]; }
    }
    __syncthreads();

    if (kh == 0) {
      unsigned short* lo = (unsigned short*)smem + (size_t)p * 2304;
      float inv = 1.0f / l_tot;
      #pragma unroll
      for (int gg = 0; gg < 8; ++gg) {
        int r = 2 * gg;
        int dl = (r & 3) + 8 * (r >> 2) + 4 * hi;
        unsigned int w0 = (unsigned int)f2bf(o0[r] * inv) | ((unsigned int)f2bf(o0[r + 1] * inv) << 16);
        unsigned int w1 = (unsigned int)f2bf(o1[r] * inv) | ((unsigned int)f2bf(o1[r + 1] * inv) << 16);
        *(unsigned int*)&lo[q * 72 + dl] = w0;
        *(unsigned int*)&lo[q * 72 + 32 + dl] = w1;
      }
      {
        int row = lane >> 1;
        int ch = (lane & 1) * 32;
        uint4 x0 = *(const uint4*)&lo[row * 72 + ch + 0];
        uint4 x1 = *(const uint4*)&lo[row * 72 + ch + 8];
        uint4 x2 = *(const uint4*)&lo[row * 72 + ch + 16];
        uint4 x3 = *(const uint4*)&lo[row * 72 + ch + 24];
        unsigned short* dst = &Ob[(size_t)(b * SEQ + wq0 + row) * (NHEADS * HDIM) + h * HDIM + ch];
        *(uint4*)(dst + 0)  = x0;
        *(uint4*)(dst + 8)  = x1;
        *(uint4*)(dst + 16) = x2;
        *(uint4*)(dst + 24) = x3;
      }
    }
  }
}

// =====================================================================
// launcher
// =====================================================================
extern "C" void kernel_launch(void* const* d_in, const int* in_sizes, int n_in,
                              void* d_out, int out_size, void* d_ws, size_t ws_size,
                              hipStream_t stream) {
  const float* X  = (const float*)d_in[0];
  const float* Wq = (const float*)d_in[1];
  const float* Wk = (const float*)d_in[2];
  const float* Wv = (const float*)d_in[3];
  const float* Wo = (const float*)d_in[4];
  float* out = (float*)d_out;

  char* ws = (char*)d_ws;
  size_t off = 0;
  auto carve = [&](size_t bytes) -> void* {
    void* p = ws + off;
    off += (bytes + 255) & ~(size_t)255;
    return p;
  };
  float* rope_cos = (float*)carve((size_t)SEQ * 32 * 4);
  float* rope_sin = (float*)carve((size_t)SEQ * 32 * 4);
  unsigned short* Xb     = (unsigned short*)carve((size_t)NTOK * HIDDEN * 2);   // reused as Ob
  unsigned short* Wqkv_t = (unsigned short*)carve((size_t)QKVN * HIDDEN * 2);
  unsigned short* Wot    = (unsigned short*)carve((size_t)HIDDEN * HIDDEN * 2);
  unsigned short* QKVb   = (unsigned short*)carve((size_t)NTOK * QKVN * 2);
  unsigned short* Vt     = (unsigned short*)carve((size_t)BATCH * NKV * HDIM * SEQ * 2);
  unsigned short* Ob     = Xb;   // Xb dead after QKV GEMM

  // fused prep: rope tables + X convert + all weight transposes
  prep_kernel<<<dim3(6912), dim3(256), 0, stream>>>(
      X, Wq, Wk, Wv, Wo, Xb, Wqkv_t, Wot, rope_cos, rope_sin);

  // QKV GEMM with fused RoPE (+ Q pre-scale) in the epilogue
  gemm128_kernel<1><<<dim3(QKVN / 128, NTOK / 128), dim3(256), 0, stream>>>(
      Xb, Wqkv_t, QKVb, NTOK, QKVN, HIDDEN, rope_cos, rope_sin);

  v_pack_kernel<<<dim3((NTOK * NKV * HDIM) / 256), dim3(256), 0, stream>>>(QKVb, Vt);

  flash_kernel<<<dim3(8, NHEADS, BATCH), dim3(512), 0, stream>>>(QKVb, Vt, Ob);

  gemm128_kernel<0><<<dim3(HIDDEN / 128, NTOK / 128), dim3(256), 0, stream>>>(
      Ob, Wot, out, NTOK, HIDDEN, HIDDEN, nullptr, nullptr);
}